// Round 21
// baseline (776.171 us; speedup 1.0000x reference)
//
#include <hip/hip_runtime.h>
#include <hip/hip_bf16.h>
#include <math.h>

// SNN forward: 64 -> 1024 -> 1024 -> 10, T=4000, B=16, LIF beta=exp(-0.025),
// thr=1, hard reset to 0, Dale clamp W>=0.
// R21: fixed SBITS false sharing (R20 postmortem: 16 blocks on 16 CUs wrote
// u64s of the SAME 128B line -> L2/XCD write ping-pong, +40us). New layout:
// SBITS[(b*16+q)*Tc + t] -- each scan_hidden block owns a private contiguous
// region. Thin GEMM v3 reads strided u64s from the 4MB L2-hot buffer.
// gemm8/scan_l0/scan_out/unpack identical to R18 (729us known-good).

#define T_STEPS 4000
#define NB 16
#define N_IN 64
#define NH 1024
#define N_OUT 10
#define SEGO 40
#define SEGH 40

typedef __attribute__((ext_vector_type(8))) short bf16x8;
typedef __attribute__((ext_vector_type(4))) float f32x4;
typedef __hip_bfloat16 bf16;
typedef unsigned long long u64;

#define ASG(p) (const __attribute__((address_space(1))) void*)(p)
#define ASL(p) (__attribute__((address_space(3))) void*)(p)

// ---------------- small utility kernels ----------------

__global__ void k_zero(float* p, int n) {
    int i = blockIdx.x * 256 + threadIdx.x;
    if (i < n) p[i] = 0.f;
}

// Build per-(t,b) 64-bit input spike masks. One wave per (t,b).
__global__ void k_mask(const float* __restrict__ in, u64* __restrict__ mask, int total) {
    int w = (blockIdx.x * 256 + threadIdx.x) >> 6;
    int lane = threadIdx.x & 63;
    if (w >= total) return;
    float v = in[(size_t)w * 64 + lane];
    u64 bal = __ballot(v > 0.5f);
    if (lane == 0) mask[w] = bal;
}

// Unpack scan_out bit-spikes: out[t][b][k] = bit (t%40) of BITS[t/40][b*16+k].
__global__ void k_unpack(const u64* __restrict__ BITS, float* __restrict__ out,
                         int total) {
    int idx = blockIdx.x * 256 + threadIdx.x;
    if (idx >= total) return;
    int t   = idx / (NB * N_OUT);
    int rem = idx - t * (NB * N_OUT);
    int b = rem / N_OUT;
    int k = rem - b * N_OUT;
    u64 w = BITS[(size_t)(t / SEGO) * 256 + b * 16 + k];
    out[idx] = ((w >> (t % SEGO)) & 1ULL) ? 1.f : 0.f;
}

// Transposing limb builder for BT1: W [1024 x 1024] -> BT [1024][2048],
// plain [hi | lo].
__global__ __launch_bounds__(256) void k_limbs_t(
    const float* __restrict__ W, bf16* __restrict__ BT) {
    __shared__ float Wlds[64][65];
    const int tid  = threadIdx.x;
    const int lane = tid & 63;
    const int wr   = tid >> 6;
    const int k0 = (blockIdx.x & 15) * 64;
    const int n0 = (blockIdx.x >> 4) * 64;
#pragma unroll
    for (int rr = 0; rr < 16; ++rr) {
        int kl = wr * 16 + rr;
        Wlds[kl][lane] = W[(size_t)(k0 + kl) * 1024 + n0 + lane];
    }
    __syncthreads();
#pragma unroll
    for (int rr = 0; rr < 16; ++rr) {
        int nl = wr * 16 + rr;
        float w = fmaxf(Wlds[lane][nl], 0.f);      // Dale's law clamp
        bf16 h = __float2bfloat16(w);
        float hf = __bfloat162float(h);
        bf16 l = __float2bfloat16(w - hf);
        size_t base = (size_t)(n0 + nl) * 2048 + k0 + lane;
        BT[base] = h;
        BT[base + 1024] = l;
    }
}

// Small limb builder (BT2): W [K x N] -> BT [Npad x 2K] plain [hi|lo].
__global__ void k_limbs(const float* __restrict__ W, bf16* __restrict__ BT,
                        int K, int N, int Npad) {
    int idx = blockIdx.x * 256 + threadIdx.x;
    int total = Npad * 2 * K;
    if (idx >= total) return;
    int n  = idx / (2 * K);
    int k2 = idx - n * (2 * K);
    int lo = (k2 >= K);
    int k = lo ? (k2 - K) : k2;
    float v = 0.f;
    if (n < N) {
        float w = fmaxf(W[(size_t)k * N + n], 0.f);
        float hi = __bfloat162float(__float2bfloat16(w));
        v = lo ? (w - hi) : w;
    }
    BT[idx] = __float2bfloat16(v);
}

// ---------------- thin GEMM v3 (layer 2): C[M x 16] = bits(A) @ BT^T -------
// A from SBITS[(b*16+q)*Tc + t] (block-contiguous layout) via LDS LUT.

__global__ __launch_bounds__(256) void k_gemm_thin(
    const u64* __restrict__ SB, const bf16* __restrict__ BT,
    float* __restrict__ C, int Tc) {
    __shared__ __align__(16) short LUT[256 * 8];
    const int tid  = threadIdx.x;
    if (tid < 256) {
        bf16x8 e;
#pragma unroll
        for (int i = 0; i < 8; ++i)
            e[i] = ((tid >> i) & 1) ? (short)0x3F80 : (short)0;
        *(bf16x8*)&LUT[tid * 8] = e;
    }
    __syncthreads();
    const int lane = tid & 63;
    const int wave = tid >> 6;
    const int r16 = lane & 15;
    const int kg  = lane >> 4;
    const int m0 = blockIdx.x * 64 + wave * 16;
    const int r  = m0 + r16;                      // row = t*16 + b
    const int bl_ = r & 15;                       // batch
    const int tl_ = r >> 4;                       // local t
    f32x4 acc = {};
    const u64* mp = SB + (size_t)(bl_ * 16) * Tc + tl_;
    const bf16* bh = BT + (size_t)r16 * 2048 + kg * 8;
    const bf16* bl = bh + 1024;
#pragma unroll 4
    for (int w = 0; w < 16; ++w) {
        u64 mk = mp[(size_t)w * Tc];
#pragma unroll
        for (int half = 0; half < 2; ++half) {
            int ka = w * 64 + half * 32;
            unsigned by = (unsigned)(mk >> (half * 32 + kg * 8)) & 0xFF;
            bf16x8 af  = *(const bf16x8*)&LUT[by * 8];
            bf16x8 bfh = *(const bf16x8*)(bh + ka);
            bf16x8 bfl = *(const bf16x8*)(bl + ka);
            acc = __builtin_amdgcn_mfma_f32_16x16x32_bf16(af, bfh, acc, 0, 0, 0);
            acc = __builtin_amdgcn_mfma_f32_16x16x32_bf16(af, bfl, acc, 0, 0, 0);
        }
    }
#pragma unroll
    for (int rr = 0; rr < 4; ++rr)
        C[(size_t)(m0 + kg * 4 + rr) * 16 + r16] = acc[rr];
}

// ---------------- 256^2 8-phase GEMM (layer 1), bf16 A (R18) ----------------
// Stage ordering invariant (R8): a region is staged only in a phase after all
// ds_reads of it have drained past a barrier (A at P3, B at P2).

__global__ __launch_bounds__(512) void k_gemm8(
    const bf16* __restrict__ A, const bf16* __restrict__ BT,
    float* __restrict__ C, int gx) {
    const int KA = 1024, K2 = 2048;
    const int kmask = KA - 1;
    const int nwg = gridDim.x;
    const int wg  = blockIdx.x;
    const int q = nwg >> 3, r = nwg & 7;
    const int xcd = wg & 7, idx0 = wg >> 3;
    const int swz = (xcd < r ? xcd * (q + 1) : r * (q + 1) + (xcd - r) * q) + idx0;
    const int gy = nwg / gx;              // 4
    const int n0 = (swz % gy) * 256;
    const int m0 = (swz / gy) * 256;

    __shared__ __align__(16) char LDS[131072];
    const int tid  = threadIdx.x;
    const int lane = tid & 63;
    const int wave = tid >> 6;
    const int wm = (wave >> 2) * 128;
    const int wn = (wave & 3) * 64;
    const int r16l = lane & 15;
    const int kg   = lane >> 4;
    const int hA   = wave >> 2;
    const int hB   = (wave & 3) >> 1;
    const int wn64 = wave & 1;

    const int po = (r16l * 64 + kg * 16) ^ (((r16l >> 3) & 1) << 5);
    const char* bA[2] = { LDS + hA * 16384 + po,
                          LDS + 65536 + hA * 16384 + po };
    const char* bB[2] = { LDS + 32768 + hB * 16384 + po,
                          LDS + 98304 + hB * 16384 + po };
    const int bOff = wn64 * 8192;

    int s_row[2], s_col[2];
#pragma unroll
    for (int rr = 0; rr < 2; ++rr) {
        int d = (rr * 512 + tid) * 16;
        int l = d ^ (((d >> 9) & 1) << 5);
        int sub = l >> 10;
        int w = l & 1023;
        s_row[rr] = (sub >> 1) * 16 + (w >> 6);
        s_col[rr] = ((sub & 1) * 64 + (w & 63)) >> 1;
    }

#define HBASE(BUF, OP, HALF) ((((BUF) * 2 + (OP)) * 2 + (HALF)) * 16384)
#define STAGE_A(BUF, HALF, K0)                                              \
    {                                                                       \
        _Pragma("unroll")                                                   \
        for (int rr = 0; rr < 2; ++rr)                                      \
            __builtin_amdgcn_global_load_lds(                               \
                ASG(A + (size_t)(m0 + (HALF) * 128 + s_row[rr]) * KA        \
                    + (((K0) + s_col[rr]) & kmask)),                        \
                ASL(LDS + HBASE(BUF, 0, HALF) + (rr * 512 + wave * 64) * 16), \
                16, 0, 0);                                                  \
    }
#define STAGE_B(BUF, HALF, K0)                                              \
    {                                                                       \
        _Pragma("unroll")                                                   \
        for (int rr = 0; rr < 2; ++rr)                                      \
            __builtin_amdgcn_global_load_lds(                               \
                ASG(BT + (size_t)(n0 + (HALF) * 128 + s_row[rr]) * K2       \
                    + (K0) + s_col[rr]),                                    \
                ASL(LDS + HBASE(BUF, 1, HALF) + (rr * 512 + wave * 64) * 16), \
                16, 0, 0);                                                  \
    }

    f32x4 acc[8][4] = {};
    bf16x8 a[4][2], b[4][2];

#define MM(MIB, NIB)                                                        \
    {                                                                       \
        _Pragma("unroll")                                                   \
        for (int i = 0; i < 4; ++i)                                         \
            _Pragma("unroll")                                               \
            for (int j = 0; j < 2; ++j) {                                   \
                acc[(MIB) + i][(NIB) + j] =                                 \
                    __builtin_amdgcn_mfma_f32_16x16x32_bf16(                \
                        a[i][0], b[(NIB) + j][0], acc[(MIB) + i][(NIB) + j], 0, 0, 0); \
                acc[(MIB) + i][(NIB) + j] =                                 \
                    __builtin_amdgcn_mfma_f32_16x16x32_bf16(                \
                        a[i][1], b[(NIB) + j][1], acc[(MIB) + i][(NIB) + j], 0, 0, 0); \
            }                                                               \
    }

#define PH_SYNC()                                                           \
    __builtin_amdgcn_s_barrier();                                           \
    asm volatile("s_waitcnt lgkmcnt(0)" ::: "memory");                      \
    __builtin_amdgcn_sched_barrier(0);

#define KTILE(BUF, SK)                                                      \
    {                                                                       \
        _Pragma("unroll")                                                   \
        for (int i = 0; i < 4; ++i) {                                       \
            a[i][0] = *(const bf16x8*)(bA[BUF] + i * 2048);                 \
            a[i][1] = *(const bf16x8*)(bA[BUF] + i * 2048 + 1024);          \
        }                                                                   \
        _Pragma("unroll")                                                   \
        for (int j = 0; j < 2; ++j) {                                       \
            b[j][0] = *(const bf16x8*)(bB[BUF] + bOff + j * 2048);          \
            b[j][1] = *(const bf16x8*)(bB[BUF] + bOff + j * 2048 + 1024);   \
        }                                                                   \
        PH_SYNC();                                                          \
        __builtin_amdgcn_s_setprio(1);                                      \
        MM(0, 0);                                                           \
        __builtin_amdgcn_s_setprio(0);                                      \
        __builtin_amdgcn_s_barrier();                                       \
        _Pragma("unroll")                                                   \
        for (int j = 0; j < 2; ++j) {                                       \
            b[2 + j][0] = *(const bf16x8*)(bB[BUF] + bOff + (2 + j) * 2048); \
            b[2 + j][1] = *(const bf16x8*)(bB[BUF] + bOff + (2 + j) * 2048 + 1024); \
        }                                                                   \
        PH_SYNC();                                                          \
        __builtin_amdgcn_s_setprio(1);                                      \
        MM(0, 2);                                                           \
        __builtin_amdgcn_s_setprio(0);                                      \
        __builtin_amdgcn_s_barrier();                                       \
        _Pragma("unroll")                                                   \
        for (int i = 0; i < 4; ++i) {                                       \
            a[i][0] = *(const bf16x8*)(bA[BUF] + (4 + i) * 2048);           \
            a[i][1] = *(const bf16x8*)(bA[BUF] + (4 + i) * 2048 + 1024);    \
        }                                                                   \
        STAGE_B(BUF, 0, SK);                                                \
        STAGE_B(BUF, 1, SK);                                                \
        PH_SYNC();                                                          \
        __builtin_amdgcn_s_setprio(1);                                      \
        MM(4, 0);                                                           \
        __builtin_amdgcn_s_setprio(0);                                      \
        __builtin_amdgcn_s_barrier();                                       \
        STAGE_A(BUF, 0, SK);                                                \
        STAGE_A(BUF, 1, SK);                                                \
        PH_SYNC();                                                          \
        __builtin_amdgcn_s_setprio(1);                                      \
        MM(4, 2);                                                           \
        __builtin_amdgcn_s_setprio(0);                                      \
        asm volatile("s_waitcnt vmcnt(8)" ::: "memory");                    \
        __builtin_amdgcn_sched_barrier(0);                                  \
        __builtin_amdgcn_s_barrier();                                       \
    }

    STAGE_A(0, 0, 0);  STAGE_A(0, 1, 0);  STAGE_B(0, 0, 0);  STAGE_B(0, 1, 0);
    STAGE_A(1, 0, 64); STAGE_A(1, 1, 64); STAGE_B(1, 0, 64); STAGE_B(1, 1, 64);
    asm volatile("s_waitcnt vmcnt(8)" ::: "memory");
    __builtin_amdgcn_sched_barrier(0);
    __builtin_amdgcn_s_barrier();

    for (int it = 0; it < 16; ++it) {
        const int k0  = it * 128;
        const int ksA = (k0 + 128) & (K2 - 1);
        const int ksB = (k0 + 192) & (K2 - 1);
        KTILE(0, ksA);
        KTILE(1, ksB);
    }
    asm volatile("s_waitcnt vmcnt(0)" ::: "memory");
    __builtin_amdgcn_sched_barrier(0);

#pragma unroll
    for (int mi = 0; mi < 8; ++mi)
#pragma unroll
        for (int ni = 0; ni < 4; ++ni)
#pragma unroll
            for (int rr = 0; rr < 4; ++rr) {
                int row = m0 + wm + mi * 16 + kg * 4 + rr;
                int col = n0 + wn + ni * 16 + r16l;
                C[(size_t)row * 1024 + col] = acc[mi][ni][rr];
            }
#undef KTILE
#undef PH_SYNC
#undef MM
#undef STAGE_A
#undef STAGE_B
#undef HBASE
}

// ---------------- LIF scan kernels (fp32 membranes) ----------------

// L0 fused scan via MFMA + mask software-pipeline; spikes to bf16 S (R18).
__global__ __launch_bounds__(64) void k_scan_l0(
    const u64* __restrict__ mask,          // [Tc][NB] for this chunk
    const float* __restrict__ W0,          // [64][1024] row-major
    const float* __restrict__ bias,
    float* __restrict__ mstate, bf16* __restrict__ S, int Tc, float beta) {
    __shared__ float Ilds[2][16][68];
    const int lane = threadIdx.x;
    const int gid  = blockIdx.x * 64 + lane;
    const int b  = blockIdx.x >> 4;
    const int q  = blockIdx.x & 15;
    const int j0 = q * 64;
    const int r16 = lane & 15;
    const int kg  = lane >> 4;
    bf16x8 bh[4][2], bl[4][2];
#pragma unroll
    for (int jt = 0; jt < 4; ++jt)
#pragma unroll
        for (int kk = 0; kk < 2; ++kk)
#pragma unroll
            for (int e = 0; e < 8; ++e) {
                int k = kk * 32 + kg * 8 + e;
                float w = fmaxf(W0[(size_t)k * 1024 + j0 + jt * 16 + r16], 0.f);
                bf16 h = __float2bfloat16(w);
                float hf = __bfloat162float(h);
                bf16 l = __float2bfloat16(w - hf);
                bh[jt][kk][e] = *(short*)&h;
                bl[jt][kk][e] = *(short*)&l;
            }
    float m = mstate[gid];
    const float bj = bias[j0 + lane];
    const size_t stride = (size_t)NB * NH;
    const int ntile = Tc / 16;
    const int tmax = ntile - 1;

#define LOADM(TT) mask[(size_t)(((TT) <= tmax ? (TT) : tmax) * 16 + r16) * NB + b]

#define L0_COMPUTE(MSK, P)                                                  \
    {                                                                       \
        f32x4 acc[4] = {};                                                  \
        _Pragma("unroll")                                                   \
        for (int kk = 0; kk < 2; ++kk) {                                    \
            unsigned byte8 = (unsigned)(((MSK) >> (kk * 32 + kg * 8)) & 0xFF); \
            bf16x8 af;                                                      \
            _Pragma("unroll")                                               \
            for (int e = 0; e < 8; ++e)                                     \
                af[e] = ((byte8 >> e) & 1) ? (short)0x3F80 : (short)0;      \
            _Pragma("unroll")                                               \
            for (int jt = 0; jt < 4; ++jt) {                                \
                acc[jt] = __builtin_amdgcn_mfma_f32_16x16x32_bf16(          \
                    af, bh[jt][kk], acc[jt], 0, 0, 0);                      \
                acc[jt] = __builtin_amdgcn_mfma_f32_16x16x32_bf16(          \
                    af, bl[jt][kk], acc[jt], 0, 0, 0);                      \
            }                                                               \
        }                                                                   \
        _Pragma("unroll")                                                   \
        for (int jt = 0; jt < 4; ++jt)                                      \
            _Pragma("unroll")                                               \
            for (int rr = 0; rr < 4; ++rr)                                  \
                Ilds[P][kg * 4 + rr][jt * 16 + r16] = acc[jt][rr];          \
    }

    u64 mc = LOADM(0);
    L0_COMPUTE(mc, 0);
    u64 mn = LOADM(1);
    for (int tt = 0; tt < ntile; ++tt) {
        __builtin_amdgcn_s_barrier();            // tile tt resident
        float v[16];
#pragma unroll
        for (int u = 0; u < 16; ++u)
            v[u] = Ilds[tt & 1][u][lane];
        u64 m2 = LOADM(tt + 2);
        if (tt + 1 < ntile) L0_COMPUTE(mn, (tt + 1) & 1);
        unsigned short o[16];
#pragma unroll
        for (int u = 0; u < 16; ++u) {
            m = fmaf(beta, m, v[u] + bj);
            bool sp = (m >= 1.0f);
            o[u] = sp ? (unsigned short)0x3F80 : (unsigned short)0;
            m = sp ? 0.f : m;
        }
#pragma unroll
        for (int u = 0; u < 16; ++u)
            ((unsigned short*)S)[(size_t)(tt * 16 + u) * stride + gid] = o[u];
        mn = m2;
    }
    mstate[gid] = m;
#undef L0_COMPUTE
#undef LOADM
}

// hidden layer 1 scan: LDS dbuf, 16B/lane staging, counted vmcnt; spikes
// emitted as ballots -> SBITS[(b*16+q)*Tc + t] (block-private region).
__global__ __launch_bounds__(64) void k_scan_hidden(
    const float* __restrict__ I, const float* __restrict__ bias,
    float* __restrict__ mstate, u64* __restrict__ SBITS, int Tc, float beta) {
    __shared__ __align__(16) float segA[SEGH * 64];
    __shared__ __align__(16) float segB[SEGH * 64];
    const int lane = threadIdx.x;
    const int gid  = blockIdx.x * 64 + lane;
    const int j = gid & (NH - 1);
    float m = mstate[gid];
    const float bj = bias[j];
    const size_t stride = (size_t)NB * NH;
    const int nseg = Tc / SEGH;                  // even
    const int lrow = lane >> 4;
    const int lcol = (lane & 15) << 2;
    u64* sb = SBITS + (size_t)blockIdx.x * Tc;   // block-private

#define H_PREFETCH(SEGBUF, SIDX)                                            \
    {                                                                       \
        const float* src = I + (size_t)(SIDX) * SEGH * stride               \
                             + (size_t)lrow * stride + blockIdx.x * 64 + lcol; \
        _Pragma("unroll")                                                   \
        for (int g = 0; g < SEGH / 4; ++g)                                  \
            __builtin_amdgcn_global_load_lds(                               \
                ASG(src + (size_t)(g * 4) * stride),                        \
                ASL(&SEGBUF[g * 256]), 16, 0, 0);                           \
    }

#define H_PROC(SEGBUF, SIDX)                                                \
    {                                                                       \
        const int btt = (SIDX) * SEGH;                                      \
        _Pragma("unroll")                                                   \
        for (int sb_ = 0; sb_ < SEGH / 8; ++sb_) {                          \
            float v[8];                                                     \
            _Pragma("unroll")                                               \
            for (int u = 0; u < 8; ++u)                                     \
                v[u] = SEGBUF[(sb_ * 8 + u) * 64 + lane];                   \
            _Pragma("unroll")                                               \
            for (int u = 0; u < 8; ++u) {                                   \
                m = fmaf(beta, m, v[u] + bj);                               \
                bool sp = (m >= 1.0f);                                      \
                u64 bal = __ballot(sp);                                     \
                if (lane == 0)                                              \
                    sb[btt + sb_ * 8 + u] = bal;                            \
                m = sp ? 0.f : m;                                           \
            }                                                               \
        }                                                                   \
    }

    H_PREFETCH(segA, 0);
    H_PREFETCH(segB, 1);
    asm volatile("s_waitcnt vmcnt(10)" ::: "memory");  // segA resident
    __builtin_amdgcn_sched_barrier(0);
    for (int s = 0; s < nseg; s += 2) {
        H_PROC(segA, s);                               // 40 stores
        if (s + 2 < nseg) {
            H_PREFETCH(segA, s + 2);
            asm volatile("s_waitcnt vmcnt(50)" ::: "memory");  // segB resident
        } else {
            asm volatile("s_waitcnt vmcnt(40)" ::: "memory");
        }
        __builtin_amdgcn_sched_barrier(0);
        H_PROC(segB, s + 1);
        if (s + 3 < nseg) {
            H_PREFETCH(segB, s + 3);
            asm volatile("s_waitcnt vmcnt(50)" ::: "memory");
            __builtin_amdgcn_sched_barrier(0);
        } else if (s + 2 < nseg) {
            asm volatile("s_waitcnt vmcnt(40)" ::: "memory");
            __builtin_amdgcn_sched_barrier(0);
        }
    }
    mstate[gid] = m;
#undef H_PREFETCH
#undef H_PROC
}

// output layer scan (once over full T): bit-packed output (R18).
__global__ __launch_bounds__(256) void k_scan_out(
    const float* __restrict__ I2, const float* __restrict__ bias,
    float* __restrict__ mstate, u64* __restrict__ BITS,
    int Tc, float beta) {
    __shared__ __align__(16) float segA[SEGO * 256];
    __shared__ __align__(16) float segB[SEGO * 256];
    const int tid  = threadIdx.x;
    const int lane = tid & 63;
    const int wave = tid >> 6;
    const int k = tid & 15;
    float m = mstate[tid];
    float bj = (k < N_OUT) ? bias[k] : 0.f;
    const int nseg = Tc / SEGO;                  // even (100)

#define O_PREFETCH(SEGBUF, SIDX)                                            \
    {                                                                       \
        const float* src = I2 + (size_t)(SIDX) * SEGO * 256                 \
                              + (size_t)wave * 256 + lane * 4;              \
        _Pragma("unroll")                                                   \
        for (int g = 0; g < SEGO / 4; ++g)                                  \
            __builtin_amdgcn_global_load_lds(                               \
                ASG(src + (size_t)(g * 4) * 256),                           \
                ASL(&SEGBUF[(g * 4 + wave) * 256]), 16, 0, 0);              \
    }

#define O_PROC(SEGBUF, SIDX)                                                \
    {                                                                       \
        u64 obits = 0;                                                      \
        _Pragma("unroll")                                                   \
        for (int sb = 0; sb < SEGO / 8; ++sb) {                             \
            float v[8];                                                     \
            _Pragma("unroll")                                               \
            for (int u = 0; u < 8; ++u)                                     \
                v[u] = SEGBUF[(sb * 8 + u) * 256 + tid];                    \
            _Pragma("unroll")                                               \
            for (int u = 0; u < 8; ++u) {                                   \
                m = fmaf(beta, m, v[u] + bj);                               \
                bool sp = (m >= 1.0f);                                      \
                obits |= ((u64)(sp ? 1 : 0)) << (sb * 8 + u);               \
                m = sp ? 0.f : m;                                           \
            }                                                               \
        }                                                                   \
        BITS[(size_t)(SIDX) * 256 + tid] = obits;                           \
    }

    O_PREFETCH(segA, 0);
    O_PREFETCH(segB, 1);
    asm volatile("s_waitcnt vmcnt(10)" ::: "memory");
    __builtin_amdgcn_sched_barrier(0);
    __builtin_amdgcn_s_barrier();
    for (int s = 0; s < nseg; s += 2) {
        O_PROC(segA, s);
        if (s + 2 < nseg) {
            O_PREFETCH(segA, s + 2);
            asm volatile("s_waitcnt vmcnt(11)" ::: "memory");
        } else {
            asm volatile("s_waitcnt vmcnt(1)" ::: "memory");
        }
        __builtin_amdgcn_sched_barrier(0);
        __builtin_amdgcn_s_barrier();
        O_PROC(segB, s + 1);
        if (s + 3 < nseg) {
            O_PREFETCH(segB, s + 3);
            asm volatile("s_waitcnt vmcnt(11)" ::: "memory");
            __builtin_amdgcn_sched_barrier(0);
            __builtin_amdgcn_s_barrier();
        } else if (s + 2 < nseg) {
            asm volatile("s_waitcnt vmcnt(1)" ::: "memory");
            __builtin_amdgcn_sched_barrier(0);
            __builtin_amdgcn_s_barrier();
        }
    }
    mstate[tid] = m;
#undef O_PREFETCH
#undef O_PROC
}

// ---------------- host ----------------

extern "C" void kernel_launch(void* const* d_in, const int* in_sizes, int n_in,
                              void* d_out, int out_size, void* d_ws, size_t ws_size,
                              hipStream_t stream) {
    const float* in_sp = (const float*)d_in[0];
    const float* W0 = (const float*)d_in[1];
    const float* b0 = (const float*)d_in[2];
    const float* W1 = (const float*)d_in[3];
    const float* b1 = (const float*)d_in[4];
    const float* W2 = (const float*)d_in[5];
    const float* b2 = (const float*)d_in[6];
    float* out = (float*)d_out;

    char* p = (char*)d_ws;
    auto carve = [&](size_t bytes) -> void* {
        char* r = p; p += (bytes + 255) & ~(size_t)255; return (void*)r;
    };
    u64*  MASK  = (u64*)carve((size_t)T_STEPS * NB * 8);
    bf16* BT1   = (bf16*)carve((size_t)NH * 2 * NH * 2);
    bf16* BT2   = (bf16*)carve((size_t)128 * 2 * NH * 2);
    float* m0s  = (float*)carve((size_t)NB * NH * 4);
    float* m1s  = (float*)carve((size_t)NB * NH * 4);
    float* m2s  = (float*)carve((size_t)NB * 16 * 4);
    float* I2BUF = (float*)carve((size_t)T_STEPS * NB * 16 * 4);  // full T
    u64*  BITS  = (u64*)carve((size_t)(T_STEPS / SEGO) * 256 * 8);
    size_t fixed = (size_t)(p - (char*)d_ws);

    // Tc | 4000, Tc % 400 == 0, Mc % 256 == 0
    const int tc_opts[3] = {2000, 800, 400};
    int Tc = 400;
    for (int i = 0; i < 3; ++i) {
        size_t Mc_ = (size_t)tc_opts[i] * NB;
        size_t need = fixed
            + ((Mc_ * NH * 4 + 255) & ~(size_t)255)     // IBUF
            + ((Mc_ * NH * 2 + 255) & ~(size_t)255)     // S (bf16)
            + ((Mc_ * 16 * 8 + 255) & ~(size_t)255);    // SBITS
        if (need <= ws_size) { Tc = tc_opts[i]; break; }
    }
    size_t Mc = (size_t)Tc * NB;
    float* IBUF  = (float*)carve(Mc * NH * 4);
    bf16*  S     = (bf16*)carve(Mc * NH * 2);
    u64*   SBITS = (u64*)carve(Mc * 16 * 8);

    const float beta = (float)exp(-0.25 / 10.0);

    int nM = NB * NH * 2 + NB * 16;
    k_zero<<<(nM + 255) / 256, 256, 0, stream>>>(m0s, nM);

    k_mask<<<(T_STEPS * NB * 64) / 256, 256, 0, stream>>>(in_sp, MASK, T_STEPS * NB);

    k_limbs_t<<<256, 256, 0, stream>>>(W1, BT1);
    k_limbs<<<(128 * 2 * NH + 255) / 256, 256, 0, stream>>>(W2, BT2, NH, N_OUT, 128);

    const int C = T_STEPS / Tc;
    const int gx8 = (int)(Mc / 256);
    const int gthin = (int)(Mc / 64);
    for (int c = 0; c < C; ++c) {
        int t0 = c * Tc;
        // layer 0: fused MFMA scan -> bf16 S
        k_scan_l0<<<256, 64, 0, stream>>>(MASK + (size_t)t0 * NB, W0, b0,
                                          m0s, S, Tc, beta);
        // layer 1: 256^2 8-phase GEMM (bf16 A from S)
        k_gemm8<<<gx8 * 4, 512, 0, stream>>>(S, BT1, IBUF, gx8);
        k_scan_hidden<<<(NB * NH) / 64, 64, 0, stream>>>(IBUF, b1, m1s, SBITS, Tc, beta);
        // layer 2: thin GEMM v3 (block-contiguous bitmask A) into full-T I2
        k_gemm_thin<<<gthin, 256, 0, stream>>>(SBITS, BT2,
                                               I2BUF + (size_t)t0 * NB * 16, Tc);
    }
    // output scan once over full T (bit-packed), then unpack
    k_scan_out<<<1, 256, 0, stream>>>(I2BUF, b2, m2s, BITS, T_STEPS, beta);
    int nOut = T_STEPS * NB * N_OUT;
    k_unpack<<<(nOut + 255) / 256, 256, 0, stream>>>(BITS, out, nOut);
}

// Round 22
// 729.161 us; speedup vs baseline: 1.0645x; 1.0645x over previous
//
#include <hip/hip_runtime.h>
#include <hip/hip_bf16.h>
#include <math.h>

// SNN forward: 64 -> 1024 -> 1024 -> 10, T=4000, B=16, LIF beta=exp(-0.025),
// thr=1, hard reset to 0, Dale clamp W>=0.
// R22: exact revert to R18 (729.3us measured best). R19/R20/R21's
// bitmask-SBITS variants of the scan_hidden->thin path all measured worse
// (770-900us) despite lower traffic; family closed. R18 structure:
// L0 fused MFMA scan + mask pipeline -> bf16 S; L1 256^2 8-phase GEMM
// (T2/T3/T4/T5, vmcnt(8)); hidden scan LDS-staged counted-vmcnt -> bf16 S;
// thin N=16 GEMM reads S; scan_out bit-packed once over full T; k_unpack.

#define T_STEPS 4000
#define NB 16
#define N_IN 64
#define NH 1024
#define N_OUT 10
#define SEGO 40           // scan_out segment rows; 10 glds + 1 bit-store
#define SEGH 40           // scan_hidden segment rows; 10 glds/segment

typedef __attribute__((ext_vector_type(8))) short bf16x8;
typedef __attribute__((ext_vector_type(4))) float f32x4;
typedef __hip_bfloat16 bf16;
typedef unsigned long long u64;

#define ASG(p) (const __attribute__((address_space(1))) void*)(p)
#define ASL(p) (__attribute__((address_space(3))) void*)(p)

// ---------------- small utility kernels ----------------

__global__ void k_zero(float* p, int n) {
    int i = blockIdx.x * 256 + threadIdx.x;
    if (i < n) p[i] = 0.f;
}

// Build per-(t,b) 64-bit input spike masks. One wave per (t,b).
__global__ void k_mask(const float* __restrict__ in, u64* __restrict__ mask, int total) {
    int w = (blockIdx.x * 256 + threadIdx.x) >> 6;
    int lane = threadIdx.x & 63;
    if (w >= total) return;
    float v = in[(size_t)w * 64 + lane];
    u64 bal = __ballot(v > 0.5f);
    if (lane == 0) mask[w] = bal;
}

// Unpack scan_out bit-spikes: out[t][b][k] = bit (t%40) of BITS[t/40][b*16+k].
__global__ void k_unpack(const u64* __restrict__ BITS, float* __restrict__ out,
                         int total) {
    int idx = blockIdx.x * 256 + threadIdx.x;
    if (idx >= total) return;
    int t   = idx / (NB * N_OUT);
    int rem = idx - t * (NB * N_OUT);
    int b = rem / N_OUT;
    int k = rem - b * N_OUT;
    u64 w = BITS[(size_t)(t / SEGO) * 256 + b * 16 + k];
    out[idx] = ((w >> (t % SEGO)) & 1ULL) ? 1.f : 0.f;
}

// Transposing limb builder for BT1: W [1024 x 1024] -> BT [1024][2048],
// plain [hi | lo].
__global__ __launch_bounds__(256) void k_limbs_t(
    const float* __restrict__ W, bf16* __restrict__ BT) {
    __shared__ float Wlds[64][65];
    const int tid  = threadIdx.x;
    const int lane = tid & 63;
    const int wr   = tid >> 6;
    const int k0 = (blockIdx.x & 15) * 64;
    const int n0 = (blockIdx.x >> 4) * 64;
#pragma unroll
    for (int rr = 0; rr < 16; ++rr) {
        int kl = wr * 16 + rr;
        Wlds[kl][lane] = W[(size_t)(k0 + kl) * 1024 + n0 + lane];
    }
    __syncthreads();
#pragma unroll
    for (int rr = 0; rr < 16; ++rr) {
        int nl = wr * 16 + rr;
        float w = fmaxf(Wlds[lane][nl], 0.f);      // Dale's law clamp
        bf16 h = __float2bfloat16(w);
        float hf = __bfloat162float(h);
        bf16 l = __float2bfloat16(w - hf);
        size_t base = (size_t)(n0 + nl) * 2048 + k0 + lane;
        BT[base] = h;
        BT[base + 1024] = l;
    }
}

// Small limb builder (BT2): W [K x N] -> BT [Npad x 2K] plain [hi|lo].
__global__ void k_limbs(const float* __restrict__ W, bf16* __restrict__ BT,
                        int K, int N, int Npad) {
    int idx = blockIdx.x * 256 + threadIdx.x;
    int total = Npad * 2 * K;
    if (idx >= total) return;
    int n  = idx / (2 * K);
    int k2 = idx - n * (2 * K);
    int lo = (k2 >= K);
    int k = lo ? (k2 - K) : k2;
    float v = 0.f;
    if (n < N) {
        float w = fmaxf(W[(size_t)k * N + n], 0.f);
        float hi = __bfloat162float(__float2bfloat16(w));
        v = lo ? (w - hi) : w;
    }
    BT[idx] = __float2bfloat16(v);
}

// ---------------- thin GEMM v2 (layer 2): C[M x 16] = A[M x 1024] @ BT^T ---
// A read ONCE per row (hi and lo B both consumed per A-frag). 64 rows/block.

__global__ __launch_bounds__(256) void k_gemm_thin(
    const bf16* __restrict__ A, const bf16* __restrict__ BT,
    float* __restrict__ C) {
    const int tid  = threadIdx.x;
    const int lane = tid & 63;
    const int wave = tid >> 6;
    const int r16 = lane & 15;
    const int kg  = lane >> 4;
    const int m0 = blockIdx.x * 64 + wave * 16;
    f32x4 acc = {};
    const bf16* ap = A + (size_t)(m0 + r16) * 1024 + kg * 8;
    const bf16* bh = BT + (size_t)r16 * 2048 + kg * 8;   // hi limb cols
    const bf16* bl = bh + 1024;                          // lo limb cols
#pragma unroll 8
    for (int kt = 0; kt < 32; ++kt) {
        const int ka = kt * 32;
        bf16x8 af  = *(const bf16x8*)(ap + ka);
        bf16x8 bfh = *(const bf16x8*)(bh + ka);
        bf16x8 bfl = *(const bf16x8*)(bl + ka);
        acc = __builtin_amdgcn_mfma_f32_16x16x32_bf16(af, bfh, acc, 0, 0, 0);
        acc = __builtin_amdgcn_mfma_f32_16x16x32_bf16(af, bfl, acc, 0, 0, 0);
    }
#pragma unroll
    for (int rr = 0; rr < 4; ++rr)
        C[(size_t)(m0 + kg * 4 + rr) * 16 + r16] = acc[rr];
}

// ---------------- 256^2 8-phase GEMM (layer 1) ----------------
// Stage ordering invariant (R8): a region is staged only in a phase after all
// ds_reads of it have drained past a barrier (A at P3, B at P2).

__global__ __launch_bounds__(512) void k_gemm8(
    const bf16* __restrict__ A, const bf16* __restrict__ BT,
    float* __restrict__ C, int gx) {
    const int KA = 1024, K2 = 2048;
    const int kmask = KA - 1;
    const int nwg = gridDim.x;
    const int wg  = blockIdx.x;
    const int q = nwg >> 3, r = nwg & 7;
    const int xcd = wg & 7, idx0 = wg >> 3;
    const int swz = (xcd < r ? xcd * (q + 1) : r * (q + 1) + (xcd - r) * q) + idx0;
    const int gy = nwg / gx;              // 4
    const int n0 = (swz % gy) * 256;
    const int m0 = (swz / gy) * 256;

    __shared__ __align__(16) char LDS[131072];
    const int tid  = threadIdx.x;
    const int lane = tid & 63;
    const int wave = tid >> 6;
    const int wm = (wave >> 2) * 128;
    const int wn = (wave & 3) * 64;
    const int r16l = lane & 15;
    const int kg   = lane >> 4;
    const int hA   = wave >> 2;
    const int hB   = (wave & 3) >> 1;
    const int wn64 = wave & 1;

    const int po = (r16l * 64 + kg * 16) ^ (((r16l >> 3) & 1) << 5);
    const char* bA[2] = { LDS + hA * 16384 + po,
                          LDS + 65536 + hA * 16384 + po };
    const char* bB[2] = { LDS + 32768 + hB * 16384 + po,
                          LDS + 98304 + hB * 16384 + po };
    const int bOff = wn64 * 8192;

    int s_row[2], s_col[2];
#pragma unroll
    for (int rr = 0; rr < 2; ++rr) {
        int d = (rr * 512 + tid) * 16;
        int l = d ^ (((d >> 9) & 1) << 5);
        int sub = l >> 10;
        int w = l & 1023;
        s_row[rr] = (sub >> 1) * 16 + (w >> 6);
        s_col[rr] = ((sub & 1) * 64 + (w & 63)) >> 1;
    }

#define HBASE(BUF, OP, HALF) ((((BUF) * 2 + (OP)) * 2 + (HALF)) * 16384)
#define STAGE_A(BUF, HALF, K0)                                              \
    {                                                                       \
        _Pragma("unroll")                                                   \
        for (int rr = 0; rr < 2; ++rr)                                      \
            __builtin_amdgcn_global_load_lds(                               \
                ASG(A + (size_t)(m0 + (HALF) * 128 + s_row[rr]) * KA        \
                    + (((K0) + s_col[rr]) & kmask)),                        \
                ASL(LDS + HBASE(BUF, 0, HALF) + (rr * 512 + wave * 64) * 16), \
                16, 0, 0);                                                  \
    }
#define STAGE_B(BUF, HALF, K0)                                              \
    {                                                                       \
        _Pragma("unroll")                                                   \
        for (int rr = 0; rr < 2; ++rr)                                      \
            __builtin_amdgcn_global_load_lds(                               \
                ASG(BT + (size_t)(n0 + (HALF) * 128 + s_row[rr]) * K2       \
                    + (K0) + s_col[rr]),                                    \
                ASL(LDS + HBASE(BUF, 1, HALF) + (rr * 512 + wave * 64) * 16), \
                16, 0, 0);                                                  \
    }

    f32x4 acc[8][4] = {};
    bf16x8 a[4][2], b[4][2];

#define MM(MIB, NIB)                                                        \
    {                                                                       \
        _Pragma("unroll")                                                   \
        for (int i = 0; i < 4; ++i)                                         \
            _Pragma("unroll")                                               \
            for (int j = 0; j < 2; ++j) {                                   \
                acc[(MIB) + i][(NIB) + j] =                                 \
                    __builtin_amdgcn_mfma_f32_16x16x32_bf16(                \
                        a[i][0], b[(NIB) + j][0], acc[(MIB) + i][(NIB) + j], 0, 0, 0); \
                acc[(MIB) + i][(NIB) + j] =                                 \
                    __builtin_amdgcn_mfma_f32_16x16x32_bf16(                \
                        a[i][1], b[(NIB) + j][1], acc[(MIB) + i][(NIB) + j], 0, 0, 0); \
            }                                                               \
    }

#define PH_SYNC()                                                           \
    __builtin_amdgcn_s_barrier();                                           \
    asm volatile("s_waitcnt lgkmcnt(0)" ::: "memory");                      \
    __builtin_amdgcn_sched_barrier(0);

#define KTILE(BUF, SK)                                                      \
    {                                                                       \
        _Pragma("unroll")                                                   \
        for (int i = 0; i < 4; ++i) {                                       \
            a[i][0] = *(const bf16x8*)(bA[BUF] + i * 2048);                 \
            a[i][1] = *(const bf16x8*)(bA[BUF] + i * 2048 + 1024);          \
        }                                                                   \
        _Pragma("unroll")                                                   \
        for (int j = 0; j < 2; ++j) {                                       \
            b[j][0] = *(const bf16x8*)(bB[BUF] + bOff + j * 2048);          \
            b[j][1] = *(const bf16x8*)(bB[BUF] + bOff + j * 2048 + 1024);   \
        }                                                                   \
        PH_SYNC();                                                          \
        __builtin_amdgcn_s_setprio(1);                                      \
        MM(0, 0);                                                           \
        __builtin_amdgcn_s_setprio(0);                                      \
        __builtin_amdgcn_s_barrier();                                       \
        _Pragma("unroll")                                                   \
        for (int j = 0; j < 2; ++j) {                                       \
            b[2 + j][0] = *(const bf16x8*)(bB[BUF] + bOff + (2 + j) * 2048); \
            b[2 + j][1] = *(const bf16x8*)(bB[BUF] + bOff + (2 + j) * 2048 + 1024); \
        }                                                                   \
        PH_SYNC();                                                          \
        __builtin_amdgcn_s_setprio(1);                                      \
        MM(0, 2);                                                           \
        __builtin_amdgcn_s_setprio(0);                                      \
        __builtin_amdgcn_s_barrier();                                       \
        _Pragma("unroll")                                                   \
        for (int i = 0; i < 4; ++i) {                                       \
            a[i][0] = *(const bf16x8*)(bA[BUF] + (4 + i) * 2048);           \
            a[i][1] = *(const bf16x8*)(bA[BUF] + (4 + i) * 2048 + 1024);    \
        }                                                                   \
        STAGE_B(BUF, 0, SK);                                                \
        STAGE_B(BUF, 1, SK);                                                \
        PH_SYNC();                                                          \
        __builtin_amdgcn_s_setprio(1);                                      \
        MM(4, 0);                                                           \
        __builtin_amdgcn_s_setprio(0);                                      \
        __builtin_amdgcn_s_barrier();                                       \
        STAGE_A(BUF, 0, SK);                                                \
        STAGE_A(BUF, 1, SK);                                                \
        PH_SYNC();                                                          \
        __builtin_amdgcn_s_setprio(1);                                      \
        MM(4, 2);                                                           \
        __builtin_amdgcn_s_setprio(0);                                      \
        asm volatile("s_waitcnt vmcnt(8)" ::: "memory");                    \
        __builtin_amdgcn_sched_barrier(0);                                  \
        __builtin_amdgcn_s_barrier();                                       \
    }

    STAGE_A(0, 0, 0);  STAGE_A(0, 1, 0);  STAGE_B(0, 0, 0);  STAGE_B(0, 1, 0);
    STAGE_A(1, 0, 64); STAGE_A(1, 1, 64); STAGE_B(1, 0, 64); STAGE_B(1, 1, 64);
    asm volatile("s_waitcnt vmcnt(8)" ::: "memory");
    __builtin_amdgcn_sched_barrier(0);
    __builtin_amdgcn_s_barrier();

    for (int it = 0; it < 16; ++it) {
        const int k0  = it * 128;
        const int ksA = (k0 + 128) & (K2 - 1);
        const int ksB = (k0 + 192) & (K2 - 1);
        KTILE(0, ksA);
        KTILE(1, ksB);
    }
    asm volatile("s_waitcnt vmcnt(0)" ::: "memory");
    __builtin_amdgcn_sched_barrier(0);

#pragma unroll
    for (int mi = 0; mi < 8; ++mi)
#pragma unroll
        for (int ni = 0; ni < 4; ++ni)
#pragma unroll
            for (int rr = 0; rr < 4; ++rr) {
                int row = m0 + wm + mi * 16 + kg * 4 + rr;
                int col = n0 + wn + ni * 16 + r16l;
                C[(size_t)row * 1024 + col] = acc[mi][ni][rr];
            }
#undef KTILE
#undef PH_SYNC
#undef MM
#undef STAGE_A
#undef STAGE_B
#undef HBASE
}

// ---------------- LIF scan kernels (fp32 membranes) ----------------

// L0 fused scan via MFMA + mask software-pipeline. 256 blocks x 64 threads.
__global__ __launch_bounds__(64) void k_scan_l0(
    const u64* __restrict__ mask,          // [Tc][NB] for this chunk
    const float* __restrict__ W0,          // [64][1024] row-major
    const float* __restrict__ bias,
    float* __restrict__ mstate, bf16* __restrict__ S, int Tc, float beta) {
    __shared__ float Ilds[2][16][68];
    const int lane = threadIdx.x;
    const int gid  = blockIdx.x * 64 + lane;   // = b*1024 + q*64 + lane
    const int b  = blockIdx.x >> 4;
    const int q  = blockIdx.x & 15;
    const int j0 = q * 64;
    const int r16 = lane & 15;
    const int kg  = lane >> 4;
    bf16x8 bh[4][2], bl[4][2];
#pragma unroll
    for (int jt = 0; jt < 4; ++jt)
#pragma unroll
        for (int kk = 0; kk < 2; ++kk)
#pragma unroll
            for (int e = 0; e < 8; ++e) {
                int k = kk * 32 + kg * 8 + e;
                float w = fmaxf(W0[(size_t)k * 1024 + j0 + jt * 16 + r16], 0.f);
                bf16 h = __float2bfloat16(w);
                float hf = __bfloat162float(h);
                bf16 l = __float2bfloat16(w - hf);
                bh[jt][kk][e] = *(short*)&h;
                bl[jt][kk][e] = *(short*)&l;
            }
    float m = mstate[gid];
    const float bj = bias[j0 + lane];
    const size_t stride = (size_t)NB * NH;
    const int ntile = Tc / 16;
    const int tmax = ntile - 1;

#define LOADM(TT) mask[(size_t)(((TT) <= tmax ? (TT) : tmax) * 16 + r16) * NB + b]

#define L0_COMPUTE(MSK, P)                                                  \
    {                                                                       \
        f32x4 acc[4] = {};                                                  \
        _Pragma("unroll")                                                   \
        for (int kk = 0; kk < 2; ++kk) {                                    \
            unsigned byte8 = (unsigned)(((MSK) >> (kk * 32 + kg * 8)) & 0xFF); \
            bf16x8 af;                                                      \
            _Pragma("unroll")                                               \
            for (int e = 0; e < 8; ++e)                                     \
                af[e] = ((byte8 >> e) & 1) ? (short)0x3F80 : (short)0;      \
            _Pragma("unroll")                                               \
            for (int jt = 0; jt < 4; ++jt) {                                \
                acc[jt] = __builtin_amdgcn_mfma_f32_16x16x32_bf16(          \
                    af, bh[jt][kk], acc[jt], 0, 0, 0);                      \
                acc[jt] = __builtin_amdgcn_mfma_f32_16x16x32_bf16(          \
                    af, bl[jt][kk], acc[jt], 0, 0, 0);                      \
            }                                                               \
        }                                                                   \
        _Pragma("unroll")                                                   \
        for (int jt = 0; jt < 4; ++jt)                                      \
            _Pragma("unroll")                                               \
            for (int rr = 0; rr < 4; ++rr)                                  \
                Ilds[P][kg * 4 + rr][jt * 16 + r16] = acc[jt][rr];          \
    }

    u64 mc = LOADM(0);
    L0_COMPUTE(mc, 0);
    u64 mn = LOADM(1);
    for (int tt = 0; tt < ntile; ++tt) {
        __builtin_amdgcn_s_barrier();            // tile tt resident
        float v[16];
#pragma unroll
        for (int u = 0; u < 16; ++u)
            v[u] = Ilds[tt & 1][u][lane];
        u64 m2 = LOADM(tt + 2);
        if (tt + 1 < ntile) L0_COMPUTE(mn, (tt + 1) & 1);
        unsigned short o[16];
#pragma unroll
        for (int u = 0; u < 16; ++u) {
            m = fmaf(beta, m, v[u] + bj);
            bool sp = (m >= 1.0f);
            o[u] = sp ? (unsigned short)0x3F80 : (unsigned short)0;
            m = sp ? 0.f : m;
        }
#pragma unroll
        for (int u = 0; u < 16; ++u)
            ((unsigned short*)S)[(size_t)(tt * 16 + u) * stride + gid] = o[u];
        mn = m2;
    }
    mstate[gid] = m;
#undef L0_COMPUTE
#undef LOADM
}

// hidden layer 1 scan: LDS double buffer, 16B/lane staging, store-aware
// counted vmcnt. S stores are 128B-coalesced per wave-instr (fast retire).
__global__ __launch_bounds__(64) void k_scan_hidden(
    const float* __restrict__ I, const float* __restrict__ bias,
    float* __restrict__ mstate, bf16* __restrict__ S, int Tc, float beta) {
    __shared__ __align__(16) float segA[SEGH * 64];
    __shared__ __align__(16) float segB[SEGH * 64];
    const int lane = threadIdx.x;
    const int gid  = blockIdx.x * 64 + lane;
    const int j = gid & (NH - 1);
    float m = mstate[gid];
    const float bj = bias[j];
    const size_t stride = (size_t)NB * NH;
    const int nseg = Tc / SEGH;                  // even
    const int lrow = lane >> 4;
    const int lcol = (lane & 15) << 2;

#define H_PREFETCH(SEGBUF, SIDX)                                            \
    {                                                                       \
        const float* src = I + (size_t)(SIDX) * SEGH * stride               \
                             + (size_t)lrow * stride + blockIdx.x * 64 + lcol; \
        _Pragma("unroll")                                                   \
        for (int g = 0; g < SEGH / 4; ++g)                                  \
            __builtin_amdgcn_global_load_lds(                               \
                ASG(src + (size_t)(g * 4) * stride),                        \
                ASL(&SEGBUF[g * 256]), 16, 0, 0);                           \
    }

#define H_PROC(SEGBUF, SIDX)                                                \
    {                                                                       \
        const int btt = (SIDX) * SEGH;                                      \
        _Pragma("unroll")                                                   \
        for (int sb = 0; sb < SEGH / 8; ++sb) {                             \
            float v[8];                                                     \
            _Pragma("unroll")                                               \
            for (int u = 0; u < 8; ++u)                                     \
                v[u] = SEGBUF[(sb * 8 + u) * 64 + lane];                    \
            unsigned short o[8];                                            \
            _Pragma("unroll")                                               \
            for (int u = 0; u < 8; ++u) {                                   \
                m = fmaf(beta, m, v[u] + bj);                               \
                bool sp = (m >= 1.0f);                                      \
                o[u] = sp ? (unsigned short)0x3F80 : (unsigned short)0;     \
                m = sp ? 0.f : m;                                           \
            }                                                               \
            _Pragma("unroll")                                               \
            for (int u = 0; u < 8; ++u)                                     \
                ((unsigned short*)S)[(size_t)(btt + sb * 8 + u) * stride + gid] = o[u]; \
        }                                                                   \
    }

    H_PREFETCH(segA, 0);
    H_PREFETCH(segB, 1);
    asm volatile("s_waitcnt vmcnt(10)" ::: "memory");  // segA resident
    __builtin_amdgcn_sched_barrier(0);
    for (int s = 0; s < nseg; s += 2) {
        H_PROC(segA, s);                               // 40 stores
        if (s + 2 < nseg) {
            H_PREFETCH(segA, s + 2);                   // 10 loads
            asm volatile("s_waitcnt vmcnt(50)" ::: "memory");  // segB resident
        } else {
            asm volatile("s_waitcnt vmcnt(40)" ::: "memory");  // segB resident
        }
        __builtin_amdgcn_sched_barrier(0);
        H_PROC(segB, s + 1);                           // 40 stores
        if (s + 3 < nseg) {
            H_PREFETCH(segB, s + 3);
            asm volatile("s_waitcnt vmcnt(50)" ::: "memory");  // segA(s+2) resident
            __builtin_amdgcn_sched_barrier(0);
        } else if (s + 2 < nseg) {
            asm volatile("s_waitcnt vmcnt(40)" ::: "memory");
            __builtin_amdgcn_sched_barrier(0);
        }
    }
    mstate[gid] = m;
#undef H_PREFETCH
#undef H_PROC
}

// output layer scan (once over full T): wave w stages rows {w+4g}, 16B/lane.
// Spikes bit-packed per segment: ONE u64 store per 40 steps -> stores leave
// the vmcnt wait path (steady vmcnt(11) = 1 store + 10 loads newer).
__global__ __launch_bounds__(256) void k_scan_out(
    const float* __restrict__ I2, const float* __restrict__ bias,
    float* __restrict__ mstate, u64* __restrict__ BITS,
    int Tc, float beta) {
    __shared__ __align__(16) float segA[SEGO * 256];
    __shared__ __align__(16) float segB[SEGO * 256];
    const int tid  = threadIdx.x;
    const int lane = tid & 63;
    const int wave = tid >> 6;
    const int k = tid & 15;
    float m = mstate[tid];
    float bj = (k < N_OUT) ? bias[k] : 0.f;
    const int nseg = Tc / SEGO;                  // even (T=4000 -> 100)

#define O_PREFETCH(SEGBUF, SIDX)                                            \
    {                                                                       \
        const float* src = I2 + (size_t)(SIDX) * SEGO * 256                 \
                              + (size_t)wave * 256 + lane * 4;              \
        _Pragma("unroll")                                                   \
        for (int g = 0; g < SEGO / 4; ++g)                                  \
            __builtin_amdgcn_global_load_lds(                               \
                ASG(src + (size_t)(g * 4) * 256),                           \
                ASL(&SEGBUF[(g * 4 + wave) * 256]), 16, 0, 0);              \
    }

#define O_PROC(SEGBUF, SIDX)                                                \
    {                                                                       \
        u64 obits = 0;                                                      \
        _Pragma("unroll")                                                   \
        for (int sb = 0; sb < SEGO / 8; ++sb) {                             \
            float v[8];                                                     \
            _Pragma("unroll")                                               \
            for (int u = 0; u < 8; ++u)                                     \
                v[u] = SEGBUF[(sb * 8 + u) * 256 + tid];                    \
            _Pragma("unroll")                                               \
            for (int u = 0; u < 8; ++u) {                                   \
                m = fmaf(beta, m, v[u] + bj);                               \
                bool sp = (m >= 1.0f);                                      \
                obits |= ((u64)(sp ? 1 : 0)) << (sb * 8 + u);               \
                m = sp ? 0.f : m;                                           \
            }                                                               \
        }                                                                   \
        BITS[(size_t)(SIDX) * 256 + tid] = obits;                           \
    }

    O_PREFETCH(segA, 0);
    O_PREFETCH(segB, 1);
    asm volatile("s_waitcnt vmcnt(10)" ::: "memory");  // segA resident
    __builtin_amdgcn_sched_barrier(0);
    __builtin_amdgcn_s_barrier();
    for (int s = 0; s < nseg; s += 2) {
        O_PROC(segA, s);                               // 1 store
        if (s + 2 < nseg) {
            O_PREFETCH(segA, s + 2);
            asm volatile("s_waitcnt vmcnt(11)" ::: "memory");  // segB resident
        } else {
            asm volatile("s_waitcnt vmcnt(1)" ::: "memory");
        }
        __builtin_amdgcn_sched_barrier(0);
        __builtin_amdgcn_s_barrier();
        O_PROC(segB, s + 1);
        if (s + 3 < nseg) {
            O_PREFETCH(segB, s + 3);
            asm volatile("s_waitcnt vmcnt(11)" ::: "memory");  // segA(s+2) resident
            __builtin_amdgcn_sched_barrier(0);
            __builtin_amdgcn_s_barrier();
        } else if (s + 2 < nseg) {
            asm volatile("s_waitcnt vmcnt(1)" ::: "memory");
            __builtin_amdgcn_sched_barrier(0);
            __builtin_amdgcn_s_barrier();
        }
    }
    mstate[tid] = m;
#undef O_PREFETCH
#undef O_PROC
}

// ---------------- host ----------------

extern "C" void kernel_launch(void* const* d_in, const int* in_sizes, int n_in,
                              void* d_out, int out_size, void* d_ws, size_t ws_size,
                              hipStream_t stream) {
    const float* in_sp = (const float*)d_in[0];
    const float* W0 = (const float*)d_in[1];
    const float* b0 = (const float*)d_in[2];
    const float* W1 = (const float*)d_in[3];
    const float* b1 = (const float*)d_in[4];
    const float* W2 = (const float*)d_in[5];
    const float* b2 = (const float*)d_in[6];
    float* out = (float*)d_out;

    char* p = (char*)d_ws;
    auto carve = [&](size_t bytes) -> void* {
        char* r = p; p += (bytes + 255) & ~(size_t)255; return (void*)r;
    };
    u64*  MASK  = (u64*)carve((size_t)T_STEPS * NB * 8);
    bf16* BT1   = (bf16*)carve((size_t)NH * 2 * NH * 2);
    bf16* BT2   = (bf16*)carve((size_t)128 * 2 * NH * 2);
    float* m0s  = (float*)carve((size_t)NB * NH * 4);
    float* m1s  = (float*)carve((size_t)NB * NH * 4);
    float* m2s  = (float*)carve((size_t)NB * 16 * 4);
    float* I2BUF = (float*)carve((size_t)T_STEPS * NB * 16 * 4);  // full T
    u64*  BITS  = (u64*)carve((size_t)(T_STEPS / SEGO) * 256 * 8);
    size_t fixed = (size_t)(p - (char*)d_ws);

    // Tc | 4000, Tc % 400 == 0, Mc % 256 == 0
    const int tc_opts[3] = {2000, 800, 400};
    int Tc = 400;
    for (int i = 0; i < 3; ++i) {
        size_t Mc_ = (size_t)tc_opts[i] * NB;
        size_t need = fixed
            + ((Mc_ * NH * 4 + 255) & ~(size_t)255)     // IBUF
            + ((Mc_ * NH * 2 + 255) & ~(size_t)255);    // S (bf16)
        if (need <= ws_size) { Tc = tc_opts[i]; break; }
    }
    size_t Mc = (size_t)Tc * NB;
    float* IBUF = (float*)carve(Mc * NH * 4);
    bf16*  S    = (bf16*)carve(Mc * NH * 2);

    const float beta = (float)exp(-0.25 / 10.0);

    int nM = NB * NH * 2 + NB * 16;
    k_zero<<<(nM + 255) / 256, 256, 0, stream>>>(m0s, nM);

    k_mask<<<(T_STEPS * NB * 64) / 256, 256, 0, stream>>>(in_sp, MASK, T_STEPS * NB);

    k_limbs_t<<<256, 256, 0, stream>>>(W1, BT1);
    k_limbs<<<(128 * 2 * NH + 255) / 256, 256, 0, stream>>>(W2, BT2, NH, N_OUT, 128);

    const int C = T_STEPS / Tc;
    const int gx8 = (int)(Mc / 256);
    const int gthin = (int)(Mc / 64);
    for (int c = 0; c < C; ++c) {
        int t0 = c * Tc;
        // layer 0: fused MFMA scan (exact fp32 via limbs)
        k_scan_l0<<<256, 64, 0, stream>>>(MASK + (size_t)t0 * NB, W0, b0,
                                          m0s, S, Tc, beta);
        // layer 1: 256^2 8-phase GEMM
        k_gemm8<<<gx8 * 4, 512, 0, stream>>>(S, BT1, IBUF, gx8);
        k_scan_hidden<<<(NB * NH) / 64, 64, 0, stream>>>(IBUF, b1, m1s, S, Tc, beta);
        // layer 2: thin GEMM v2 into the full-T I2 buffer
        k_gemm_thin<<<gthin, 256, 0, stream>>>(S, BT2,
                                               I2BUF + (size_t)t0 * NB * 16);
    }
    // output scan once over full T (bit-packed), then unpack to floats
    k_scan_out<<<1, 256, 0, stream>>>(I2BUF, b2, m2s, BITS, T_STEPS, beta);
    int nOut = T_STEPS * NB * N_OUT;
    k_unpack<<<(nOut + 255) / 256, 256, 0, stream>>>(BITS, out, nOut);
}

// Round 23
// 672.148 us; speedup vs baseline: 1.1548x; 1.0848x over previous
//
#include <hip/hip_runtime.h>
#include <hip/hip_bf16.h>
#include <math.h>

// SNN forward: 64 -> 1024 -> 1024 -> 10, T=4000, B=16, LIF beta=exp(-0.025),
// thr=1, hard reset to 0, Dale clamp W>=0.
// R23 (on R22=R18 baseline, 729us): (1) per-chunk scan_out, with chunk c's
// scan_out merged as an extra block into gemm8(c+1)'s grid -- it runs
// concurrently under the 133us GEMM (only the final chunk's scan_out is
// exposed, ~21us). Tail block: waves 0-3 do the work, waves 4-7 join
// barriers only (uniform control flow). (2) prep kernels (zero/mask/
// limbs_t/limbs) merged into ONE launch. Everything else identical to R22.

#define T_STEPS 4000
#define NB 16
#define N_IN 64
#define NH 1024
#define N_OUT 10
#define SEGO 40           // scan_out segment rows; 10 glds + 1 bit-store
#define SEGH 40           // scan_hidden segment rows; 10 glds/segment

typedef __attribute__((ext_vector_type(8))) short bf16x8;
typedef __attribute__((ext_vector_type(4))) float f32x4;
typedef __hip_bfloat16 bf16;
typedef unsigned long long u64;

#define ASG(p) (const __attribute__((address_space(1))) void*)(p)
#define ASL(p) (__attribute__((address_space(3))) void*)(p)

// ---------------- merged prep kernel ----------------
// block ranges: [0,ZB) zero mstates | [ZB,ZB+MB) input masks |
// [.., +256) limbs_t BT1 | rest: limbs BT2.

__global__ __launch_bounds__(256) void k_prep(
    const float* __restrict__ in_sp, u64* __restrict__ mask,
    const float* __restrict__ W1, bf16* __restrict__ BT1,
    const float* __restrict__ W2, bf16* __restrict__ BT2,
    float* __restrict__ mst, int nM, int ZB, int MB) {
    __shared__ float Wlds[64][65];
    int b = blockIdx.x;
    const int tid = threadIdx.x;
    if (b < ZB) {                                  // zero membrane states
        int i = b * 256 + tid;
        if (i < nM) mst[i] = 0.f;
        return;
    }
    b -= ZB;
    if (b < MB) {                                  // input spike masks
        int w = b * 4 + (tid >> 6);
        int lane = tid & 63;
        float v = in_sp[(size_t)w * 64 + lane];
        u64 bal = __ballot(v > 0.5f);
        if (lane == 0) mask[w] = bal;
        return;
    }
    b -= MB;
    if (b < 256) {                                 // limbs_t: BT1 [1024][2048]
        const int lane = tid & 63;
        const int wr   = tid >> 6;
        const int k0 = (b & 15) * 64;
        const int n0 = (b >> 4) * 64;
#pragma unroll
        for (int rr = 0; rr < 16; ++rr) {
            int kl = wr * 16 + rr;
            Wlds[kl][lane] = W1[(size_t)(k0 + kl) * 1024 + n0 + lane];
        }
        __syncthreads();
#pragma unroll
        for (int rr = 0; rr < 16; ++rr) {
            int nl = wr * 16 + rr;
            float w = fmaxf(Wlds[lane][nl], 0.f);  // Dale's law clamp
            bf16 h = __float2bfloat16(w);
            float hf = __bfloat162float(h);
            bf16 l = __float2bfloat16(w - hf);
            size_t base = (size_t)(n0 + nl) * 2048 + k0 + lane;
            BT1[base] = h;
            BT1[base + 1024] = l;
        }
        return;
    }
    b -= 256;
    {                                              // limbs: BT2 [128][2048]
        int idx = b * 256 + tid;
        int total = 128 * 2 * NH;
        if (idx >= total) return;
        int n  = idx / (2 * NH);
        int k2 = idx - n * (2 * NH);
        int lo = (k2 >= NH);
        int k = lo ? (k2 - NH) : k2;
        float v = 0.f;
        if (n < N_OUT) {
            float w = fmaxf(W2[(size_t)k * N_OUT + n], 0.f);
            float hi = __bfloat162float(__float2bfloat16(w));
            v = lo ? (w - hi) : w;
        }
        BT2[idx] = __float2bfloat16(v);
    }
}

// Unpack scan_out bit-spikes: out[t][b][k] = bit (t%40) of BITS[t/40][b*16+k].
__global__ void k_unpack(const u64* __restrict__ BITS, float* __restrict__ out,
                         int total) {
    int idx = blockIdx.x * 256 + threadIdx.x;
    if (idx >= total) return;
    int t   = idx / (NB * N_OUT);
    int rem = idx - t * (NB * N_OUT);
    int b = rem / N_OUT;
    int k = rem - b * N_OUT;
    u64 w = BITS[(size_t)(t / SEGO) * 256 + b * 16 + k];
    out[idx] = ((w >> (t % SEGO)) & 1ULL) ? 1.f : 0.f;
}

// ---------------- scan_out body (shared by standalone + gemm8 tail) --------
// Bit-packed output (R18): one u64 store per 40 steps. Works with >=256
// threads: tid<256 are active; extra waves join waits/barriers only.

__device__ __forceinline__ void scan_out_body(
    const float* __restrict__ I2, const float* __restrict__ bias,
    float* __restrict__ mstate, u64* __restrict__ BITS,
    int Tc, float* seg, int tid) {
    float* segA = seg;
    float* segB = seg + SEGO * 256;
    const bool act = tid < 256;
    const int lane = tid & 63;
    const int wave = tid >> 6;                   // 0..3 active
    const int k = tid & 15;
    float m = 0.f, bj = 0.f;
    if (act) {
        m = mstate[tid];
        bj = (k < N_OUT) ? bias[k] : 0.f;
    }
    const int nseg = Tc / SEGO;                  // even

#define O_PREFETCH(SEGBUF, SIDX)                                            \
    if (act) {                                                              \
        const float* src = I2 + (size_t)(SIDX) * SEGO * 256                 \
                              + (size_t)wave * 256 + lane * 4;              \
        _Pragma("unroll")                                                   \
        for (int g = 0; g < SEGO / 4; ++g)                                  \
            __builtin_amdgcn_global_load_lds(                               \
                ASG(src + (size_t)(g * 4) * 256),                           \
                ASL(&SEGBUF[(g * 4 + wave) * 256]), 16, 0, 0);              \
    }

#define O_PROC(SEGBUF, SIDX)                                                \
    if (act) {                                                              \
        u64 obits = 0;                                                      \
        _Pragma("unroll")                                                   \
        for (int sb = 0; sb < SEGO / 8; ++sb) {                             \
            float v[8];                                                     \
            _Pragma("unroll")                                               \
            for (int u = 0; u < 8; ++u)                                     \
                v[u] = SEGBUF[(sb * 8 + u) * 256 + tid];                    \
            _Pragma("unroll")                                               \
            for (int u = 0; u < 8; ++u) {                                   \
                m = fmaf(beta_c, m, v[u] + bj);                             \
                bool sp = (m >= 1.0f);                                      \
                obits |= ((u64)(sp ? 1 : 0)) << (sb * 8 + u);               \
                m = sp ? 0.f : m;                                           \
            }                                                               \
        }                                                                   \
        BITS[(size_t)(SIDX) * 256 + tid] = obits;                           \
    }

    const float beta_c = 0.97530991202833261687f;   // exp(-0.025)
    O_PREFETCH(segA, 0);
    O_PREFETCH(segB, 1);
    asm volatile("s_waitcnt vmcnt(10)" ::: "memory");  // segA resident
    __builtin_amdgcn_sched_barrier(0);
    __builtin_amdgcn_s_barrier();
    for (int s = 0; s < nseg; s += 2) {
        O_PROC(segA, s);                               // 1 store
        if (s + 2 < nseg) {
            O_PREFETCH(segA, s + 2);
            asm volatile("s_waitcnt vmcnt(11)" ::: "memory");  // segB resident
        } else {
            asm volatile("s_waitcnt vmcnt(1)" ::: "memory");
        }
        __builtin_amdgcn_sched_barrier(0);
        __builtin_amdgcn_s_barrier();
        O_PROC(segB, s + 1);
        if (s + 3 < nseg) {
            O_PREFETCH(segB, s + 3);
            asm volatile("s_waitcnt vmcnt(11)" ::: "memory");  // segA(s+2) resident
            __builtin_amdgcn_sched_barrier(0);
            __builtin_amdgcn_s_barrier();
        } else if (s + 2 < nseg) {
            asm volatile("s_waitcnt vmcnt(1)" ::: "memory");
            __builtin_amdgcn_sched_barrier(0);
            __builtin_amdgcn_s_barrier();
        }
    }
    if (act) mstate[tid] = m;
#undef O_PREFETCH
#undef O_PROC
}

// standalone scan_out (final chunk)
__global__ __launch_bounds__(256) void k_scan_out(
    const float* __restrict__ I2, const float* __restrict__ bias,
    float* __restrict__ mstate, u64* __restrict__ BITS, int Tc) {
    __shared__ __align__(16) float seg[2 * SEGO * 256];
    scan_out_body(I2, bias, mstate, BITS, Tc, seg, threadIdx.x);
}

// ---------------- thin GEMM v2 (layer 2): C[M x 16] = A[M x 1024] @ BT^T ---

__global__ __launch_bounds__(256) void k_gemm_thin(
    const bf16* __restrict__ A, const bf16* __restrict__ BT,
    float* __restrict__ C) {
    const int tid  = threadIdx.x;
    const int lane = tid & 63;
    const int wave = tid >> 6;
    const int r16 = lane & 15;
    const int kg  = lane >> 4;
    const int m0 = blockIdx.x * 64 + wave * 16;
    f32x4 acc = {};
    const bf16* ap = A + (size_t)(m0 + r16) * 1024 + kg * 8;
    const bf16* bh = BT + (size_t)r16 * 2048 + kg * 8;   // hi limb cols
    const bf16* bl = bh + 1024;                          // lo limb cols
#pragma unroll 8
    for (int kt = 0; kt < 32; ++kt) {
        const int ka = kt * 32;
        bf16x8 af  = *(const bf16x8*)(ap + ka);
        bf16x8 bfh = *(const bf16x8*)(bh + ka);
        bf16x8 bfl = *(const bf16x8*)(bl + ka);
        acc = __builtin_amdgcn_mfma_f32_16x16x32_bf16(af, bfh, acc, 0, 0, 0);
        acc = __builtin_amdgcn_mfma_f32_16x16x32_bf16(af, bfl, acc, 0, 0, 0);
    }
#pragma unroll
    for (int rr = 0; rr < 4; ++rr)
        C[(size_t)(m0 + kg * 4 + rr) * 16 + r16] = acc[rr];
}

// ---------------- 256^2 8-phase GEMM (layer 1) + optional scan_out tail ----
// Stage ordering invariant (R8): a region is staged only in a phase after all
// ds_reads of it have drained past a barrier (A at P3, B at P2).

__global__ __launch_bounds__(512) void k_gemm8(
    const bf16* __restrict__ A, const bf16* __restrict__ BT,
    float* __restrict__ C, int gx,
    const float* __restrict__ I2t, const float* __restrict__ b2t,
    float* __restrict__ m2t, u64* __restrict__ BITSt, int tcT, int doTail) {
    __shared__ __align__(16) char LDS[131072];
    const int tid  = threadIdx.x;

    if (doTail && (int)blockIdx.x == (int)gridDim.x - 1) {
        scan_out_body(I2t, b2t, m2t, BITSt, tcT, (float*)LDS, tid);
        return;
    }

    const int KA = 1024, K2 = 2048;
    const int kmask = KA - 1;
    const int nwg = gridDim.x - doTail;
    const int wg  = blockIdx.x;
    const int q = nwg >> 3, r = nwg & 7;
    const int xcd = wg & 7, idx0 = wg >> 3;
    const int swz = (xcd < r ? xcd * (q + 1) : r * (q + 1) + (xcd - r) * q) + idx0;
    const int gy = nwg / gx;              // 4
    const int n0 = (swz % gy) * 256;
    const int m0 = (swz / gy) * 256;

    const int lane = tid & 63;
    const int wave = tid >> 6;
    const int wm = (wave >> 2) * 128;
    const int wn = (wave & 3) * 64;
    const int r16l = lane & 15;
    const int kg   = lane >> 4;
    const int hA   = wave >> 2;
    const int hB   = (wave & 3) >> 1;
    const int wn64 = wave & 1;

    const int po = (r16l * 64 + kg * 16) ^ (((r16l >> 3) & 1) << 5);
    const char* bA[2] = { LDS + hA * 16384 + po,
                          LDS + 65536 + hA * 16384 + po };
    const char* bB[2] = { LDS + 32768 + hB * 16384 + po,
                          LDS + 98304 + hB * 16384 + po };
    const int bOff = wn64 * 8192;

    int s_row[2], s_col[2];
#pragma unroll
    for (int rr = 0; rr < 2; ++rr) {
        int d = (rr * 512 + tid) * 16;
        int l = d ^ (((d >> 9) & 1) << 5);
        int sub = l >> 10;
        int w = l & 1023;
        s_row[rr] = (sub >> 1) * 16 + (w >> 6);
        s_col[rr] = ((sub & 1) * 64 + (w & 63)) >> 1;
    }

#define HBASE(BUF, OP, HALF) ((((BUF) * 2 + (OP)) * 2 + (HALF)) * 16384)
#define STAGE_A(BUF, HALF, K0)                                              \
    {                                                                       \
        _Pragma("unroll")                                                   \
        for (int rr = 0; rr < 2; ++rr)                                      \
            __builtin_amdgcn_global_load_lds(                               \
                ASG(A + (size_t)(m0 + (HALF) * 128 + s_row[rr]) * KA        \
                    + (((K0) + s_col[rr]) & kmask)),                        \
                ASL(LDS + HBASE(BUF, 0, HALF) + (rr * 512 + wave * 64) * 16), \
                16, 0, 0);                                                  \
    }
#define STAGE_B(BUF, HALF, K0)                                              \
    {                                                                       \
        _Pragma("unroll")                                                   \
        for (int rr = 0; rr < 2; ++rr)                                      \
            __builtin_amdgcn_global_load_lds(                               \
                ASG(BT + (size_t)(n0 + (HALF) * 128 + s_row[rr]) * K2       \
                    + (K0) + s_col[rr]),                                    \
                ASL(LDS + HBASE(BUF, 1, HALF) + (rr * 512 + wave * 64) * 16), \
                16, 0, 0);                                                  \
    }

    f32x4 acc[8][4] = {};
    bf16x8 a[4][2], b[4][2];

#define MM(MIB, NIB)                                                        \
    {                                                                       \
        _Pragma("unroll")                                                   \
        for (int i = 0; i < 4; ++i)                                         \
            _Pragma("unroll")                                               \
            for (int j = 0; j < 2; ++j) {                                   \
                acc[(MIB) + i][(NIB) + j] =                                 \
                    __builtin_amdgcn_mfma_f32_16x16x32_bf16(                \
                        a[i][0], b[(NIB) + j][0], acc[(MIB) + i][(NIB) + j], 0, 0, 0); \
                acc[(MIB) + i][(NIB) + j] =                                 \
                    __builtin_amdgcn_mfma_f32_16x16x32_bf16(                \
                        a[i][1], b[(NIB) + j][1], acc[(MIB) + i][(NIB) + j], 0, 0, 0); \
            }                                                               \
    }

#define PH_SYNC()                                                           \
    __builtin_amdgcn_s_barrier();                                           \
    asm volatile("s_waitcnt lgkmcnt(0)" ::: "memory");                      \
    __builtin_amdgcn_sched_barrier(0);

#define KTILE(BUF, SK)                                                      \
    {                                                                       \
        _Pragma("unroll")                                                   \
        for (int i = 0; i < 4; ++i) {                                       \
            a[i][0] = *(const bf16x8*)(bA[BUF] + i * 2048);                 \
            a[i][1] = *(const bf16x8*)(bA[BUF] + i * 2048 + 1024);          \
        }                                                                   \
        _Pragma("unroll")                                                   \
        for (int j = 0; j < 2; ++j) {                                       \
            b[j][0] = *(const bf16x8*)(bB[BUF] + bOff + j * 2048);          \
            b[j][1] = *(const bf16x8*)(bB[BUF] + bOff + j * 2048 + 1024);   \
        }                                                                   \
        PH_SYNC();                                                          \
        __builtin_amdgcn_s_setprio(1);                                      \
        MM(0, 0);                                                           \
        __builtin_amdgcn_s_setprio(0);                                      \
        __builtin_amdgcn_s_barrier();                                       \
        _Pragma("unroll")                                                   \
        for (int j = 0; j < 2; ++j) {                                       \
            b[2 + j][0] = *(const bf16x8*)(bB[BUF] + bOff + (2 + j) * 2048); \
            b[2 + j][1] = *(const bf16x8*)(bB[BUF] + bOff + (2 + j) * 2048 + 1024); \
        }                                                                   \
        PH_SYNC();                                                          \
        __builtin_amdgcn_s_setprio(1);                                      \
        MM(0, 2);                                                           \
        __builtin_amdgcn_s_setprio(0);                                      \
        __builtin_amdgcn_s_barrier();                                       \
        _Pragma("unroll")                                                   \
        for (int i = 0; i < 4; ++i) {                                       \
            a[i][0] = *(const bf16x8*)(bA[BUF] + (4 + i) * 2048);           \
            a[i][1] = *(const bf16x8*)(bA[BUF] + (4 + i) * 2048 + 1024);    \
        }                                                                   \
        STAGE_B(BUF, 0, SK);                                                \
        STAGE_B(BUF, 1, SK);                                                \
        PH_SYNC();                                                          \
        __builtin_amdgcn_s_setprio(1);                                      \
        MM(4, 0);                                                           \
        __builtin_amdgcn_s_setprio(0);                                      \
        __builtin_amdgcn_s_barrier();                                       \
        STAGE_A(BUF, 0, SK);                                                \
        STAGE_A(BUF, 1, SK);                                                \
        PH_SYNC();                                                          \
        __builtin_amdgcn_s_setprio(1);                                      \
        MM(4, 2);                                                           \
        __builtin_amdgcn_s_setprio(0);                                      \
        asm volatile("s_waitcnt vmcnt(8)" ::: "memory");                    \
        __builtin_amdgcn_sched_barrier(0);                                  \
        __builtin_amdgcn_s_barrier();                                       \
    }

    STAGE_A(0, 0, 0);  STAGE_A(0, 1, 0);  STAGE_B(0, 0, 0);  STAGE_B(0, 1, 0);
    STAGE_A(1, 0, 64); STAGE_A(1, 1, 64); STAGE_B(1, 0, 64); STAGE_B(1, 1, 64);
    asm volatile("s_waitcnt vmcnt(8)" ::: "memory");
    __builtin_amdgcn_sched_barrier(0);
    __builtin_amdgcn_s_barrier();

    for (int it = 0; it < 16; ++it) {
        const int k0  = it * 128;
        const int ksA = (k0 + 128) & (K2 - 1);
        const int ksB = (k0 + 192) & (K2 - 1);
        KTILE(0, ksA);
        KTILE(1, ksB);
    }
    asm volatile("s_waitcnt vmcnt(0)" ::: "memory");
    __builtin_amdgcn_sched_barrier(0);

#pragma unroll
    for (int mi = 0; mi < 8; ++mi)
#pragma unroll
        for (int ni = 0; ni < 4; ++ni)
#pragma unroll
            for (int rr = 0; rr < 4; ++rr) {
                int row = m0 + wm + mi * 16 + kg * 4 + rr;
                int col = n0 + wn + ni * 16 + r16l;
                C[(size_t)row * 1024 + col] = acc[mi][ni][rr];
            }
#undef KTILE
#undef PH_SYNC
#undef MM
#undef STAGE_A
#undef STAGE_B
#undef HBASE
}

// ---------------- LIF scan kernels (fp32 membranes) ----------------

// L0 fused scan via MFMA + mask software-pipeline. 256 blocks x 64 threads.
__global__ __launch_bounds__(64) void k_scan_l0(
    const u64* __restrict__ mask,          // [Tc][NB] for this chunk
    const float* __restrict__ W0,          // [64][1024] row-major
    const float* __restrict__ bias,
    float* __restrict__ mstate, bf16* __restrict__ S, int Tc, float beta) {
    __shared__ float Ilds[2][16][68];
    const int lane = threadIdx.x;
    const int gid  = blockIdx.x * 64 + lane;   // = b*1024 + q*64 + lane
    const int b  = blockIdx.x >> 4;
    const int q  = blockIdx.x & 15;
    const int j0 = q * 64;
    const int r16 = lane & 15;
    const int kg  = lane >> 4;
    bf16x8 bh[4][2], bl[4][2];
#pragma unroll
    for (int jt = 0; jt < 4; ++jt)
#pragma unroll
        for (int kk = 0; kk < 2; ++kk)
#pragma unroll
            for (int e = 0; e < 8; ++e) {
                int k = kk * 32 + kg * 8 + e;
                float w = fmaxf(W0[(size_t)k * 1024 + j0 + jt * 16 + r16], 0.f);
                bf16 h = __float2bfloat16(w);
                float hf = __bfloat162float(h);
                bf16 l = __float2bfloat16(w - hf);
                bh[jt][kk][e] = *(short*)&h;
                bl[jt][kk][e] = *(short*)&l;
            }
    float m = mstate[gid];
    const float bj = bias[j0 + lane];
    const size_t stride = (size_t)NB * NH;
    const int ntile = Tc / 16;
    const int tmax = ntile - 1;

#define LOADM(TT) mask[(size_t)(((TT) <= tmax ? (TT) : tmax) * 16 + r16) * NB + b]

#define L0_COMPUTE(MSK, P)                                                  \
    {                                                                       \
        f32x4 acc[4] = {};                                                  \
        _Pragma("unroll")                                                   \
        for (int kk = 0; kk < 2; ++kk) {                                    \
            unsigned byte8 = (unsigned)(((MSK) >> (kk * 32 + kg * 8)) & 0xFF); \
            bf16x8 af;                                                      \
            _Pragma("unroll")                                               \
            for (int e = 0; e < 8; ++e)                                     \
                af[e] = ((byte8 >> e) & 1) ? (short)0x3F80 : (short)0;      \
            _Pragma("unroll")                                               \
            for (int jt = 0; jt < 4; ++jt) {                                \
                acc[jt] = __builtin_amdgcn_mfma_f32_16x16x32_bf16(          \
                    af, bh[jt][kk], acc[jt], 0, 0, 0);                      \
                acc[jt] = __builtin_amdgcn_mfma_f32_16x16x32_bf16(          \
                    af, bl[jt][kk], acc[jt], 0, 0, 0);                      \
            }                                                               \
        }                                                                   \
        _Pragma("unroll")                                                   \
        for (int jt = 0; jt < 4; ++jt)                                      \
            _Pragma("unroll")                                               \
            for (int rr = 0; rr < 4; ++rr)                                  \
                Ilds[P][kg * 4 + rr][jt * 16 + r16] = acc[jt][rr];          \
    }

    u64 mc = LOADM(0);
    L0_COMPUTE(mc, 0);
    u64 mn = LOADM(1);
    for (int tt = 0; tt < ntile; ++tt) {
        __builtin_amdgcn_s_barrier();            // tile tt resident
        float v[16];
#pragma unroll
        for (int u = 0; u < 16; ++u)
            v[u] = Ilds[tt & 1][u][lane];
        u64 m2 = LOADM(tt + 2);
        if (tt + 1 < ntile) L0_COMPUTE(mn, (tt + 1) & 1);
        unsigned short o[16];
#pragma unroll
        for (int u = 0; u < 16; ++u) {
            m = fmaf(beta, m, v[u] + bj);
            bool sp = (m >= 1.0f);
            o[u] = sp ? (unsigned short)0x3F80 : (unsigned short)0;
            m = sp ? 0.f : m;
        }
#pragma unroll
        for (int u = 0; u < 16; ++u)
            ((unsigned short*)S)[(size_t)(tt * 16 + u) * stride + gid] = o[u];
        mn = m2;
    }
    mstate[gid] = m;
#undef L0_COMPUTE
#undef LOADM
}

// hidden layer 1 scan: LDS double buffer, 16B/lane staging, store-aware
// counted vmcnt.
__global__ __launch_bounds__(64) void k_scan_hidden(
    const float* __restrict__ I, const float* __restrict__ bias,
    float* __restrict__ mstate, bf16* __restrict__ S, int Tc, float beta) {
    __shared__ __align__(16) float segA[SEGH * 64];
    __shared__ __align__(16) float segB[SEGH * 64];
    const int lane = threadIdx.x;
    const int gid  = blockIdx.x * 64 + lane;
    const int j = gid & (NH - 1);
    float m = mstate[gid];
    const float bj = bias[j];
    const size_t stride = (size_t)NB * NH;
    const int nseg = Tc / SEGH;                  // even
    const int lrow = lane >> 4;
    const int lcol = (lane & 15) << 2;

#define H_PREFETCH(SEGBUF, SIDX)                                            \
    {                                                                       \
        const float* src = I + (size_t)(SIDX) * SEGH * stride               \
                             + (size_t)lrow * stride + blockIdx.x * 64 + lcol; \
        _Pragma("unroll")                                                   \
        for (int g = 0; g < SEGH / 4; ++g)                                  \
            __builtin_amdgcn_global_load_lds(                               \
                ASG(src + (size_t)(g * 4) * stride),                        \
                ASL(&SEGBUF[g * 256]), 16, 0, 0);                           \
    }

#define H_PROC(SEGBUF, SIDX)                                                \
    {                                                                       \
        const int btt = (SIDX) * SEGH;                                      \
        _Pragma("unroll")                                                   \
        for (int sb = 0; sb < SEGH / 8; ++sb) {                             \
            float v[8];                                                     \
            _Pragma("unroll")                                               \
            for (int u = 0; u < 8; ++u)                                     \
                v[u] = SEGBUF[(sb * 8 + u) * 64 + lane];                    \
            unsigned short o[8];                                            \
            _Pragma("unroll")                                               \
            for (int u = 0; u < 8; ++u) {                                   \
                m = fmaf(beta, m, v[u] + bj);                               \
                bool sp = (m >= 1.0f);                                      \
                o[u] = sp ? (unsigned short)0x3F80 : (unsigned short)0;     \
                m = sp ? 0.f : m;                                           \
            }                                                               \
            _Pragma("unroll")                                               \
            for (int u = 0; u < 8; ++u)                                     \
                ((unsigned short*)S)[(size_t)(btt + sb * 8 + u) * stride + gid] = o[u]; \
        }                                                                   \
    }

    H_PREFETCH(segA, 0);
    H_PREFETCH(segB, 1);
    asm volatile("s_waitcnt vmcnt(10)" ::: "memory");  // segA resident
    __builtin_amdgcn_sched_barrier(0);
    for (int s = 0; s < nseg; s += 2) {
        H_PROC(segA, s);                               // 40 stores
        if (s + 2 < nseg) {
            H_PREFETCH(segA, s + 2);                   // 10 loads
            asm volatile("s_waitcnt vmcnt(50)" ::: "memory");  // segB resident
        } else {
            asm volatile("s_waitcnt vmcnt(40)" ::: "memory");  // segB resident
        }
        __builtin_amdgcn_sched_barrier(0);
        H_PROC(segB, s + 1);                           // 40 stores
        if (s + 3 < nseg) {
            H_PREFETCH(segB, s + 3);
            asm volatile("s_waitcnt vmcnt(50)" ::: "memory");  // segA(s+2) resident
            __builtin_amdgcn_sched_barrier(0);
        } else if (s + 2 < nseg) {
            asm volatile("s_waitcnt vmcnt(40)" ::: "memory");
            __builtin_amdgcn_sched_barrier(0);
        }
    }
    mstate[gid] = m;
#undef H_PREFETCH
#undef H_PROC
}

// ---------------- host ----------------

extern "C" void kernel_launch(void* const* d_in, const int* in_sizes, int n_in,
                              void* d_out, int out_size, void* d_ws, size_t ws_size,
                              hipStream_t stream) {
    const float* in_sp = (const float*)d_in[0];
    const float* W0 = (const float*)d_in[1];
    const float* b0 = (const float*)d_in[2];
    const float* W1 = (const float*)d_in[3];
    const float* b1 = (const float*)d_in[4];
    const float* W2 = (const float*)d_in[5];
    const float* b2 = (const float*)d_in[6];
    float* out = (float*)d_out;

    char* p = (char*)d_ws;
    auto carve = [&](size_t bytes) -> void* {
        char* r = p; p += (bytes + 255) & ~(size_t)255; return (void*)r;
    };
    u64*  MASK  = (u64*)carve((size_t)T_STEPS * NB * 8);
    bf16* BT1   = (bf16*)carve((size_t)NH * 2 * NH * 2);
    bf16* BT2   = (bf16*)carve((size_t)128 * 2 * NH * 2);
    float* m0s  = (float*)carve((size_t)NB * NH * 4);
    float* m1s  = (float*)carve((size_t)NB * NH * 4);
    float* m2s  = (float*)carve((size_t)NB * 16 * 4);
    float* I2BUF = (float*)carve((size_t)T_STEPS * NB * 16 * 4);  // full T
    u64*  BITS  = (u64*)carve((size_t)(T_STEPS / SEGO) * 256 * 8);
    size_t fixed = (size_t)(p - (char*)d_ws);

    // Tc | 4000, Tc % 400 == 0, Mc % 256 == 0
    const int tc_opts[3] = {2000, 800, 400};
    int Tc = 400;
    for (int i = 0; i < 3; ++i) {
        size_t Mc_ = (size_t)tc_opts[i] * NB;
        size_t need = fixed
            + ((Mc_ * NH * 4 + 255) & ~(size_t)255)     // IBUF
            + ((Mc_ * NH * 2 + 255) & ~(size_t)255);    // S (bf16)
        if (need <= ws_size) { Tc = tc_opts[i]; break; }
    }
    size_t Mc = (size_t)Tc * NB;
    float* IBUF = (float*)carve(Mc * NH * 4);
    bf16*  S    = (bf16*)carve(Mc * NH * 2);

    const float beta = (float)exp(-0.25 / 10.0);

    // merged prep: zero states + input masks + BT1 + BT2 in ONE launch
    int nM = NB * NH * 2 + NB * 16;
    const int ZB = (nM + 255) / 256;
    const int MB = (T_STEPS * NB) / 4;
    const int L2B = (128 * 2 * NH + 255) / 256;
    k_prep<<<ZB + MB + 256 + L2B, 256, 0, stream>>>(
        in_sp, MASK, W1, BT1, W2, BT2, m0s, nM, ZB, MB);

    const int C = T_STEPS / Tc;
    const int gx8 = (int)(Mc / 256);
    const int gthin = (int)(Mc / 64);
    for (int c = 0; c < C; ++c) {
        int t0 = c * Tc;
        // layer 0: fused MFMA scan (exact fp32 via limbs)
        k_scan_l0<<<256, 64, 0, stream>>>(MASK + (size_t)t0 * NB, W0, b0,
                                          m0s, S, Tc, beta);
        // layer 1: 256^2 8-phase GEMM; carries previous chunk's scan_out as
        // one extra block (runs concurrently, fully hidden under the GEMM)
        if (c == 0) {
            k_gemm8<<<gx8 * 4, 512, 0, stream>>>(S, BT1, IBUF, gx8,
                                                 nullptr, nullptr, nullptr,
                                                 nullptr, 0, 0);
        } else {
            int tp = (c - 1) * Tc;
            k_gemm8<<<gx8 * 4 + 1, 512, 0, stream>>>(
                S, BT1, IBUF, gx8,
                I2BUF + (size_t)tp * NB * 16, b2, m2s,
                BITS + (size_t)(tp / SEGO) * 256, Tc, 1);
        }
        k_scan_hidden<<<(NB * NH) / 64, 64, 0, stream>>>(IBUF, b1, m1s, S, Tc, beta);
        // layer 2: thin GEMM v2 into the full-T I2 buffer
        k_gemm_thin<<<gthin, 256, 0, stream>>>(S, BT2,
                                               I2BUF + (size_t)t0 * NB * 16);
    }
    // final chunk's output scan (bit-packed), then unpack to floats
    int tl = (C - 1) * Tc;
    k_scan_out<<<1, 256, 0, stream>>>(I2BUF + (size_t)tl * NB * 16, b2, m2s,
                                      BITS + (size_t)(tl / SEGO) * 256, Tc);
    int nOut = T_STEPS * NB * N_OUT;
    k_unpack<<<(nOut + 255) / 256, 256, 0, stream>>>(BITS, out, nOut);
}

// Round 24
// 658.461 us; speedup vs baseline: 1.1788x; 1.0208x over previous
//
#include <hip/hip_runtime.h>
#include <hip/hip_bf16.h>
#include <math.h>

// SNN forward: 64 -> 1024 -> 1024 -> 10, T=4000, B=16, LIF beta=exp(-0.025),
// thr=1, hard reset to 0, Dale clamp W>=0.
// R24 (on R23, 672us): limb-INTERLEAVED BT1 ([hi64|lo64] per source k-tile)
// so both KTILEs of a gemm8 iteration share ONE A tile: A staged once/iter
// (was twice), A LDS double-buffered by iteration parity, kmask removed.
// Waits re-derived: end-of-EVEN vmcnt(8), end-of-ODD vmcnt(4), prologue
// vmcnt(4). R23 features kept: scan_out(c) hidden as tail block of
// gemm8(c+1); merged prep; bit-packed output + unpack.

#define T_STEPS 4000
#define NB 16
#define N_IN 64
#define NH 1024
#define N_OUT 10
#define SEGO 40           // scan_out segment rows; 10 glds + 1 bit-store
#define SEGH 40           // scan_hidden segment rows; 10 glds/segment

typedef __attribute__((ext_vector_type(8))) short bf16x8;
typedef __attribute__((ext_vector_type(4))) float f32x4;
typedef __hip_bfloat16 bf16;
typedef unsigned long long u64;

#define ASG(p) (const __attribute__((address_space(1))) void*)(p)
#define ASL(p) (__attribute__((address_space(3))) void*)(p)

// ---------------- merged prep kernel ----------------
// block ranges: [0,ZB) zero mstates | [ZB,ZB+MB) input masks |
// [.., +256) limbs_t BT1 (INTERLEAVED) | rest: limbs BT2 (plain).

__global__ __launch_bounds__(256) void k_prep(
    const float* __restrict__ in_sp, u64* __restrict__ mask,
    const float* __restrict__ W1, bf16* __restrict__ BT1,
    const float* __restrict__ W2, bf16* __restrict__ BT2,
    float* __restrict__ mst, int nM, int ZB, int MB) {
    __shared__ float Wlds[64][65];
    int b = blockIdx.x;
    const int tid = threadIdx.x;
    if (b < ZB) {                                  // zero membrane states
        int i = b * 256 + tid;
        if (i < nM) mst[i] = 0.f;
        return;
    }
    b -= ZB;
    if (b < MB) {                                  // input spike masks
        int w = b * 4 + (tid >> 6);
        int lane = tid & 63;
        float v = in_sp[(size_t)w * 64 + lane];
        u64 bal = __ballot(v > 0.5f);
        if (lane == 0) mask[w] = bal;
        return;
    }
    b -= MB;
    if (b < 256) {                                 // limbs_t: BT1 interleaved
        const int lane = tid & 63;
        const int wr   = tid >> 6;
        const int k0 = (b & 15) * 64;
        const int n0 = (b >> 4) * 64;
#pragma unroll
        for (int rr = 0; rr < 16; ++rr) {
            int kl = wr * 16 + rr;
            Wlds[kl][lane] = W1[(size_t)(k0 + kl) * 1024 + n0 + lane];
        }
        __syncthreads();
#pragma unroll
        for (int rr = 0; rr < 16; ++rr) {
            int nl = wr * 16 + rr;
            float w = fmaxf(Wlds[lane][nl], 0.f);  // Dale's law clamp
            bf16 h = __float2bfloat16(w);
            float hf = __bfloat162float(h);
            bf16 l = __float2bfloat16(w - hf);
            // interleaved: hi at 2*k0 + lane, lo at +64 (per 64-tile)
            size_t base = (size_t)(n0 + nl) * 2048 + 2 * k0 + lane;
            BT1[base] = h;
            BT1[base + 64] = l;
        }
        return;
    }
    b -= 256;
    {                                              // limbs: BT2 [128][2048]
        int idx = b * 256 + tid;
        int total = 128 * 2 * NH;
        if (idx >= total) return;
        int n  = idx / (2 * NH);
        int k2 = idx - n * (2 * NH);
        int lo = (k2 >= NH);
        int k = lo ? (k2 - NH) : k2;
        float v = 0.f;
        if (n < N_OUT) {
            float w = fmaxf(W2[(size_t)k * N_OUT + n], 0.f);
            float hi = __bfloat162float(__float2bfloat16(w));
            v = lo ? (w - hi) : w;
        }
        BT2[idx] = __float2bfloat16(v);
    }
}

// Unpack scan_out bit-spikes: out[t][b][k] = bit (t%40) of BITS[t/40][b*16+k].
__global__ void k_unpack(const u64* __restrict__ BITS, float* __restrict__ out,
                         int total) {
    int idx = blockIdx.x * 256 + threadIdx.x;
    if (idx >= total) return;
    int t   = idx / (NB * N_OUT);
    int rem = idx - t * (NB * N_OUT);
    int b = rem / N_OUT;
    int k = rem - b * N_OUT;
    u64 w = BITS[(size_t)(t / SEGO) * 256 + b * 16 + k];
    out[idx] = ((w >> (t % SEGO)) & 1ULL) ? 1.f : 0.f;
}

// ---------------- scan_out body (shared by standalone + gemm8 tail) --------

__device__ __forceinline__ void scan_out_body(
    const float* __restrict__ I2, const float* __restrict__ bias,
    float* __restrict__ mstate, u64* __restrict__ BITS,
    int Tc, float* seg, int tid) {
    float* segA = seg;
    float* segB = seg + SEGO * 256;
    const bool act = tid < 256;
    const int lane = tid & 63;
    const int wave = tid >> 6;                   // 0..3 active
    const int k = tid & 15;
    float m = 0.f, bj = 0.f;
    if (act) {
        m = mstate[tid];
        bj = (k < N_OUT) ? bias[k] : 0.f;
    }
    const int nseg = Tc / SEGO;                  // even

#define O_PREFETCH(SEGBUF, SIDX)                                            \
    if (act) {                                                              \
        const float* src = I2 + (size_t)(SIDX) * SEGO * 256                 \
                              + (size_t)wave * 256 + lane * 4;              \
        _Pragma("unroll")                                                   \
        for (int g = 0; g < SEGO / 4; ++g)                                  \
            __builtin_amdgcn_global_load_lds(                               \
                ASG(src + (size_t)(g * 4) * 256),                           \
                ASL(&SEGBUF[(g * 4 + wave) * 256]), 16, 0, 0);              \
    }

#define O_PROC(SEGBUF, SIDX)                                                \
    if (act) {                                                              \
        u64 obits = 0;                                                      \
        _Pragma("unroll")                                                   \
        for (int sb = 0; sb < SEGO / 8; ++sb) {                             \
            float v[8];                                                     \
            _Pragma("unroll")                                               \
            for (int u = 0; u < 8; ++u)                                     \
                v[u] = SEGBUF[(sb * 8 + u) * 256 + tid];                    \
            _Pragma("unroll")                                               \
            for (int u = 0; u < 8; ++u) {                                   \
                m = fmaf(beta_c, m, v[u] + bj);                             \
                bool sp = (m >= 1.0f);                                      \
                obits |= ((u64)(sp ? 1 : 0)) << (sb * 8 + u);               \
                m = sp ? 0.f : m;                                           \
            }                                                               \
        }                                                                   \
        BITS[(size_t)(SIDX) * 256 + tid] = obits;                           \
    }

    const float beta_c = 0.97530991202833261687f;   // exp(-0.025)
    O_PREFETCH(segA, 0);
    O_PREFETCH(segB, 1);
    asm volatile("s_waitcnt vmcnt(10)" ::: "memory");  // segA resident
    __builtin_amdgcn_sched_barrier(0);
    __builtin_amdgcn_s_barrier();
    for (int s = 0; s < nseg; s += 2) {
        O_PROC(segA, s);                               // 1 store
        if (s + 2 < nseg) {
            O_PREFETCH(segA, s + 2);
            asm volatile("s_waitcnt vmcnt(11)" ::: "memory");  // segB resident
        } else {
            asm volatile("s_waitcnt vmcnt(1)" ::: "memory");
        }
        __builtin_amdgcn_sched_barrier(0);
        __builtin_amdgcn_s_barrier();
        O_PROC(segB, s + 1);
        if (s + 3 < nseg) {
            O_PREFETCH(segB, s + 3);
            asm volatile("s_waitcnt vmcnt(11)" ::: "memory");  // segA(s+2) resident
            __builtin_amdgcn_sched_barrier(0);
            __builtin_amdgcn_s_barrier();
        } else if (s + 2 < nseg) {
            asm volatile("s_waitcnt vmcnt(1)" ::: "memory");
            __builtin_amdgcn_sched_barrier(0);
            __builtin_amdgcn_s_barrier();
        }
    }
    if (act) mstate[tid] = m;
#undef O_PREFETCH
#undef O_PROC
}

// standalone scan_out (final chunk)
__global__ __launch_bounds__(256) void k_scan_out(
    const float* __restrict__ I2, const float* __restrict__ bias,
    float* __restrict__ mstate, u64* __restrict__ BITS, int Tc) {
    __shared__ __align__(16) float seg[2 * SEGO * 256];
    scan_out_body(I2, bias, mstate, BITS, Tc, seg, threadIdx.x);
}

// ---------------- thin GEMM v2 (layer 2): C[M x 16] = A[M x 1024] @ BT^T ---

__global__ __launch_bounds__(256) void k_gemm_thin(
    const bf16* __restrict__ A, const bf16* __restrict__ BT,
    float* __restrict__ C) {
    const int tid  = threadIdx.x;
    const int lane = tid & 63;
    const int wave = tid >> 6;
    const int r16 = lane & 15;
    const int kg  = lane >> 4;
    const int m0 = blockIdx.x * 64 + wave * 16;
    f32x4 acc = {};
    const bf16* ap = A + (size_t)(m0 + r16) * 1024 + kg * 8;
    const bf16* bh = BT + (size_t)r16 * 2048 + kg * 8;   // hi limb cols
    const bf16* bl = bh + 1024;                          // lo limb cols
#pragma unroll 8
    for (int kt = 0; kt < 32; ++kt) {
        const int ka = kt * 32;
        bf16x8 af  = *(const bf16x8*)(ap + ka);
        bf16x8 bfh = *(const bf16x8*)(bh + ka);
        bf16x8 bfl = *(const bf16x8*)(bl + ka);
        acc = __builtin_amdgcn_mfma_f32_16x16x32_bf16(af, bfh, acc, 0, 0, 0);
        acc = __builtin_amdgcn_mfma_f32_16x16x32_bf16(af, bfl, acc, 0, 0, 0);
    }
#pragma unroll
    for (int rr = 0; rr < 4; ++rr)
        C[(size_t)(m0 + kg * 4 + rr) * 16 + r16] = acc[rr];
}

// ---------------- 256^2 8-phase GEMM (layer 1), shared-A iteration ---------
// BT1 interleaved: iteration it = KTILE kt=2it (hi) + kt=2it+1 (lo), both
// consuming A source tile it. A LDS double-buffered by it parity (2x32KB);
// B double-buffered by KTILE parity (2x32KB). Stage schedule per iteration:
// EVEN.P2: B_even@it+1; EVEN.P3: A@it+1; ODD.P2: B_odd@it+1.
// Waits: end-of-EVEN vmcnt(8); end-of-ODD vmcnt(4); prologue vmcnt(4).
// WAR invariant (R8): each staged region's prior reads drained past >=1
// all-wave barrier before its stage issues.

__global__ __launch_bounds__(512) void k_gemm8(
    const bf16* __restrict__ A, const bf16* __restrict__ BT,
    float* __restrict__ C, int gx,
    const float* __restrict__ I2t, const float* __restrict__ b2t,
    float* __restrict__ m2t, u64* __restrict__ BITSt, int tcT, int doTail) {
    __shared__ __align__(16) char LDS[131072];
    const int tid  = threadIdx.x;

    if (doTail && (int)blockIdx.x == (int)gridDim.x - 1) {
        scan_out_body(I2t, b2t, m2t, BITSt, tcT, (float*)LDS, tid);
        return;
    }

    const int KA = 1024;
    const int nwg = gridDim.x - doTail;
    const int wg  = blockIdx.x;
    const int q = nwg >> 3, r = nwg & 7;
    const int xcd = wg & 7, idx0 = wg >> 3;
    const int swz = (xcd < r ? xcd * (q + 1) : r * (q + 1) + (xcd - r) * q) + idx0;
    const int gy = nwg / gx;              // 4
    const int n0 = (swz % gy) * 256;
    const int m0 = (swz / gy) * 256;

    const int lane = tid & 63;
    const int wave = tid >> 6;
    const int wm = (wave >> 2) * 128;
    const int wn = (wave & 3) * 64;
    const int r16l = lane & 15;
    const int kg   = lane >> 4;
    const int hA   = wave >> 2;
    const int hB   = (wave & 3) >> 1;
    const int wn64 = wave & 1;

    const int po = (r16l * 64 + kg * 16) ^ (((r16l >> 3) & 1) << 5);
    const char* bA[2] = { LDS + hA * 16384 + po,             // A[0]
                          LDS + 32768 + hA * 16384 + po };   // A[1]
    const char* bB[2] = { LDS + 65536 + hB * 16384 + po,     // B[0] (even kt)
                          LDS + 98304 + hB * 16384 + po };   // B[1] (odd kt)
    const int bOff = wn64 * 8192;

    int s_row[2], s_col[2];
#pragma unroll
    for (int rr = 0; rr < 2; ++rr) {
        int d = (rr * 512 + tid) * 16;
        int l = d ^ (((d >> 9) & 1) << 5);
        int sub = l >> 10;
        int w = l & 1023;
        s_row[rr] = (sub >> 1) * 16 + (w >> 6);
        s_col[rr] = ((sub & 1) * 64 + (w & 63)) >> 1;
    }

#define STAGE_A(ADST, HALF, K0)                                             \
    {                                                                       \
        _Pragma("unroll")                                                   \
        for (int rr = 0; rr < 2; ++rr)                                      \
            __builtin_amdgcn_global_load_lds(                               \
                ASG(A + (size_t)(m0 + (HALF) * 128 + s_row[rr]) * KA        \
                    + (K0) + s_col[rr]),                                    \
                ASL(LDS + (ADST) * 32768 + (HALF) * 16384                   \
                    + (rr * 512 + wave * 64) * 16),                         \
                16, 0, 0);                                                  \
    }
#define STAGE_B(BUF, HALF, K0)                                              \
    {                                                                       \
        _Pragma("unroll")                                                   \
        for (int rr = 0; rr < 2; ++rr)                                      \
            __builtin_amdgcn_global_load_lds(                               \
                ASG(BT + (size_t)(n0 + (HALF) * 128 + s_row[rr]) * 2048     \
                    + (K0) + s_col[rr]),                                    \
                ASL(LDS + 65536 + (BUF) * 32768 + (HALF) * 16384            \
                    + (rr * 512 + wave * 64) * 16),                         \
                16, 0, 0);                                                  \
    }

    f32x4 acc[8][4] = {};
    bf16x8 a[4][2], b[4][2];

#define MM(MIB, NIB)                                                        \
    {                                                                       \
        _Pragma("unroll")                                                   \
        for (int i = 0; i < 4; ++i)                                         \
            _Pragma("unroll")                                               \
            for (int j = 0; j < 2; ++j) {                                   \
                acc[(MIB) + i][(NIB) + j] =                                 \
                    __builtin_amdgcn_mfma_f32_16x16x32_bf16(                \
                        a[i][0], b[(NIB) + j][0], acc[(MIB) + i][(NIB) + j], 0, 0, 0); \
                acc[(MIB) + i][(NIB) + j] =                                 \
                    __builtin_amdgcn_mfma_f32_16x16x32_bf16(                \
                        a[i][1], b[(NIB) + j][1], acc[(MIB) + i][(NIB) + j], 0, 0, 0); \
            }                                                               \
    }

#define PH_SYNC()                                                           \
    __builtin_amdgcn_s_barrier();                                           \
    asm volatile("s_waitcnt lgkmcnt(0)" ::: "memory");                      \
    __builtin_amdgcn_sched_barrier(0);

// even KTILE of iteration (A buf = ABUF): stages B_even@next (P2) and
// A@next into A[ABUF^1] (P3); closing wait vmcnt(8).
#define KT_EVEN(ABUF, BKN, AKN)                                             \
    {                                                                       \
        _Pragma("unroll")                                                   \
        for (int i = 0; i < 4; ++i) {                                       \
            a[i][0] = *(const bf16x8*)(bA[ABUF] + i * 2048);                \
            a[i][1] = *(const bf16x8*)(bA[ABUF] + i * 2048 + 1024);         \
        }                                                                   \
        _Pragma("unroll")                                                   \
        for (int j = 0; j < 2; ++j) {                                       \
            b[j][0] = *(const bf16x8*)(bB[0] + bOff + j * 2048);            \
            b[j][1] = *(const bf16x8*)(bB[0] + bOff + j * 2048 + 1024);     \
        }                                                                   \
        PH_SYNC();                                                          \
        __builtin_amdgcn_s_setprio(1);                                      \
        MM(0, 0);                                                           \
        __builtin_amdgcn_s_setprio(0);                                      \
        __builtin_amdgcn_s_barrier();                                       \
        _Pragma("unroll")                                                   \
        for (int j = 0; j < 2; ++j) {                                       \
            b[2 + j][0] = *(const bf16x8*)(bB[0] + bOff + (2 + j) * 2048);  \
            b[2 + j][1] = *(const bf16x8*)(bB[0] + bOff + (2 + j) * 2048 + 1024); \
        }                                                                   \
        PH_SYNC();                                                          \
        __builtin_amdgcn_s_setprio(1);                                      \
        MM(0, 2);                                                           \
        __builtin_amdgcn_s_setprio(0);                                      \
        __builtin_amdgcn_s_barrier();                                       \
        _Pragma("unroll")                                                   \
        for (int i = 0; i < 4; ++i) {                                       \
            a[i][0] = *(const bf16x8*)(bA[ABUF] + (4 + i) * 2048);          \
            a[i][1] = *(const bf16x8*)(bA[ABUF] + (4 + i) * 2048 + 1024);   \
        }                                                                   \
        STAGE_B(0, 0, BKN);                                                 \
        STAGE_B(0, 1, BKN);                                                 \
        PH_SYNC();                                                          \
        __builtin_amdgcn_s_setprio(1);                                      \
        MM(4, 0);                                                           \
        __builtin_amdgcn_s_setprio(0);                                      \
        __builtin_amdgcn_s_barrier();                                       \
        STAGE_A((ABUF) ^ 1, 0, AKN);                                        \
        STAGE_A((ABUF) ^ 1, 1, AKN);                                        \
        PH_SYNC();                                                          \
        __builtin_amdgcn_s_setprio(1);                                      \
        MM(4, 2);                                                           \
        __builtin_amdgcn_s_setprio(0);                                      \
        asm volatile("s_waitcnt vmcnt(8)" ::: "memory");                    \
        __builtin_amdgcn_sched_barrier(0);                                  \
        __builtin_amdgcn_s_barrier();                                       \
    }

// odd KTILE (same A buf): stages B_odd@next (P2); closing wait vmcnt(4).
#define KT_ODD(ABUF, BKN)                                                   \
    {                                                                       \
        _Pragma("unroll")                                                   \
        for (int i = 0; i < 4; ++i) {                                       \
            a[i][0] = *(const bf16x8*)(bA[ABUF] + i * 2048);                \
            a[i][1] = *(const bf16x8*)(bA[ABUF] + i * 2048 + 1024);         \
        }                                                                   \
        _Pragma("unroll")                                                   \
        for (int j = 0; j < 2; ++j) {                                       \
            b[j][0] = *(const bf16x8*)(bB[1] + bOff + j * 2048);            \
            b[j][1] = *(const bf16x8*)(bB[1] + bOff + j * 2048 + 1024);     \
        }                                                                   \
        PH_SYNC();                                                          \
        __builtin_amdgcn_s_setprio(1);                                      \
        MM(0, 0);                                                           \
        __builtin_amdgcn_s_setprio(0);                                      \
        __builtin_amdgcn_s_barrier();                                       \
        _Pragma("unroll")                                                   \
        for (int j = 0; j < 2; ++j) {                                       \
            b[2 + j][0] = *(const bf16x8*)(bB[1] + bOff + (2 + j) * 2048);  \
            b[2 + j][1] = *(const bf16x8*)(bB[1] + bOff + (2 + j) * 2048 + 1024); \
        }                                                                   \
        PH_SYNC();                                                          \
        __builtin_amdgcn_s_setprio(1);                                      \
        MM(0, 2);                                                           \
        __builtin_amdgcn_s_setprio(0);                                      \
        __builtin_amdgcn_s_barrier();                                       \
        _Pragma("unroll")                                                   \
        for (int i = 0; i < 4; ++i) {                                       \
            a[i][0] = *(const bf16x8*)(bA[ABUF] + (4 + i) * 2048);          \
            a[i][1] = *(const bf16x8*)(bA[ABUF] + (4 + i) * 2048 + 1024);   \
        }                                                                   \
        STAGE_B(1, 0, BKN);                                                 \
        STAGE_B(1, 1, BKN);                                                 \
        PH_SYNC();                                                          \
        __builtin_amdgcn_s_setprio(1);                                      \
        MM(4, 0);                                                           \
        __builtin_amdgcn_s_setprio(0);                                      \
        __builtin_amdgcn_s_barrier();                                       \
        PH_SYNC();                                                          \
        __builtin_amdgcn_s_setprio(1);                                      \
        MM(4, 2);                                                           \
        __builtin_amdgcn_s_setprio(0);                                      \
        asm volatile("s_waitcnt vmcnt(4)" ::: "memory");                    \
        __builtin_amdgcn_sched_barrier(0);                                  \
        __builtin_amdgcn_s_barrier();                                       \
    }

    // prologue: B_even@0, A@0 -> A[0], B_odd@0; wait oldest 8 (vmcnt(4))
    STAGE_B(0, 0, 0);  STAGE_B(0, 1, 0);
    STAGE_A(0, 0, 0);  STAGE_A(0, 1, 0);
    STAGE_B(1, 0, 64); STAGE_B(1, 1, 64);
    asm volatile("s_waitcnt vmcnt(4)" ::: "memory");
    __builtin_amdgcn_sched_barrier(0);
    __builtin_amdgcn_s_barrier();

    for (int it2 = 0; it2 < 16; it2 += 2) {
        // iteration it2 (A buf 0)
        const int ak1 = (64 * (it2 + 1)) & 1023;
        const int be1 = (128 * (it2 + 1)) & 2047;
        KT_EVEN(0, be1, ak1);
        KT_ODD(0, be1 + 64);
        // iteration it2+1 (A buf 1)
        const int ak2 = (64 * (it2 + 2)) & 1023;
        const int be2 = (128 * (it2 + 2)) & 2047;
        KT_EVEN(1, be2, ak2);
        KT_ODD(1, be2 + 64);
    }
    asm volatile("s_waitcnt vmcnt(0)" ::: "memory");
    __builtin_amdgcn_sched_barrier(0);

#pragma unroll
    for (int mi = 0; mi < 8; ++mi)
#pragma unroll
        for (int ni = 0; ni < 4; ++ni)
#pragma unroll
            for (int rr = 0; rr < 4; ++rr) {
                int row = m0 + wm + mi * 16 + kg * 4 + rr;
                int col = n0 + wn + ni * 16 + r16l;
                C[(size_t)row * 1024 + col] = acc[mi][ni][rr];
            }
#undef KT_ODD
#undef KT_EVEN
#undef PH_SYNC
#undef MM
#undef STAGE_A
#undef STAGE_B
}

// ---------------- LIF scan kernels (fp32 membranes) ----------------

// L0 fused scan via MFMA + mask software-pipeline. 256 blocks x 64 threads.
__global__ __launch_bounds__(64) void k_scan_l0(
    const u64* __restrict__ mask,          // [Tc][NB] for this chunk
    const float* __restrict__ W0,          // [64][1024] row-major
    const float* __restrict__ bias,
    float* __restrict__ mstate, bf16* __restrict__ S, int Tc, float beta) {
    __shared__ float Ilds[2][16][68];
    const int lane = threadIdx.x;
    const int gid  = blockIdx.x * 64 + lane;   // = b*1024 + q*64 + lane
    const int b  = blockIdx.x >> 4;
    const int q  = blockIdx.x & 15;
    const int j0 = q * 64;
    const int r16 = lane & 15;
    const int kg  = lane >> 4;
    bf16x8 bh[4][2], bl[4][2];
#pragma unroll
    for (int jt = 0; jt < 4; ++jt)
#pragma unroll
        for (int kk = 0; kk < 2; ++kk)
#pragma unroll
            for (int e = 0; e < 8; ++e) {
                int k = kk * 32 + kg * 8 + e;
                float w = fmaxf(W0[(size_t)k * 1024 + j0 + jt * 16 + r16], 0.f);
                bf16 h = __float2bfloat16(w);
                float hf = __bfloat162float(h);
                bf16 l = __float2bfloat16(w - hf);
                bh[jt][kk][e] = *(short*)&h;
                bl[jt][kk][e] = *(short*)&l;
            }
    float m = mstate[gid];
    const float bj = bias[j0 + lane];
    const size_t stride = (size_t)NB * NH;
    const int ntile = Tc / 16;
    const int tmax = ntile - 1;

#define LOADM(TT) mask[(size_t)(((TT) <= tmax ? (TT) : tmax) * 16 + r16) * NB + b]

#define L0_COMPUTE(MSK, P)                                                  \
    {                                                                       \
        f32x4 acc[4] = {};                                                  \
        _Pragma("unroll")                                                   \
        for (int kk = 0; kk < 2; ++kk) {                                    \
            unsigned byte8 = (unsigned)(((MSK) >> (kk * 32 + kg * 8)) & 0xFF); \
            bf16x8 af;                                                      \
            _Pragma("unroll")                                               \
            for (int e = 0; e < 8; ++e)                                     \
                af[e] = ((byte8 >> e) & 1) ? (short)0x3F80 : (short)0;      \
            _Pragma("unroll")                                               \
            for (int jt = 0; jt < 4; ++jt) {                                \
                acc[jt] = __builtin_amdgcn_mfma_f32_16x16x32_bf16(          \
                    af, bh[jt][kk], acc[jt], 0, 0, 0);                      \
                acc[jt] = __builtin_amdgcn_mfma_f32_16x16x32_bf16(          \
                    af, bl[jt][kk], acc[jt], 0, 0, 0);                      \
            }                                                               \
        }                                                                   \
        _Pragma("unroll")                                                   \
        for (int jt = 0; jt < 4; ++jt)                                      \
            _Pragma("unroll")                                               \
            for (int rr = 0; rr < 4; ++rr)                                  \
                Ilds[P][kg * 4 + rr][jt * 16 + r16] = acc[jt][rr];          \
    }

    u64 mc = LOADM(0);
    L0_COMPUTE(mc, 0);
    u64 mn = LOADM(1);
    for (int tt = 0; tt < ntile; ++tt) {
        __builtin_amdgcn_s_barrier();            // tile tt resident
        float v[16];
#pragma unroll
        for (int u = 0; u < 16; ++u)
            v[u] = Ilds[tt & 1][u][lane];
        u64 m2 = LOADM(tt + 2);
        if (tt + 1 < ntile) L0_COMPUTE(mn, (tt + 1) & 1);
        unsigned short o[16];
#pragma unroll
        for (int u = 0; u < 16; ++u) {
            m = fmaf(beta, m, v[u] + bj);
            bool sp = (m >= 1.0f);
            o[u] = sp ? (unsigned short)0x3F80 : (unsigned short)0;
            m = sp ? 0.f : m;
        }
#pragma unroll
        for (int u = 0; u < 16; ++u)
            ((unsigned short*)S)[(size_t)(tt * 16 + u) * stride + gid] = o[u];
        mn = m2;
    }
    mstate[gid] = m;
#undef L0_COMPUTE
#undef LOADM
}

// hidden layer 1 scan: LDS double buffer, 16B/lane staging, store-aware
// counted vmcnt.
__global__ __launch_bounds__(64) void k_scan_hidden(
    const float* __restrict__ I, const float* __restrict__ bias,
    float* __restrict__ mstate, bf16* __restrict__ S, int Tc, float beta) {
    __shared__ __align__(16) float segA[SEGH * 64];
    __shared__ __align__(16) float segB[SEGH * 64];
    const int lane = threadIdx.x;
    const int gid  = blockIdx.x * 64 + lane;
    const int j = gid & (NH - 1);
    float m = mstate[gid];
    const float bj = bias[j];
    const size_t stride = (size_t)NB * NH;
    const int nseg = Tc / SEGH;                  // even
    const int lrow = lane >> 4;
    const int lcol = (lane & 15) << 2;

#define H_PREFETCH(SEGBUF, SIDX)                                            \
    {                                                                       \
        const float* src = I + (size_t)(SIDX) * SEGH * stride               \
                             + (size_t)lrow * stride + blockIdx.x * 64 + lcol; \
        _Pragma("unroll")                                                   \
        for (int g = 0; g < SEGH / 4; ++g)                                  \
            __builtin_amdgcn_global_load_lds(                               \
                ASG(src + (size_t)(g * 4) * stride),                        \
                ASL(&SEGBUF[g * 256]), 16, 0, 0);                           \
    }

#define H_PROC(SEGBUF, SIDX)                                                \
    {                                                                       \
        const int btt = (SIDX) * SEGH;                                      \
        _Pragma("unroll")                                                   \
        for (int sb = 0; sb < SEGH / 8; ++sb) {                             \
            float v[8];                                                     \
            _Pragma("unroll")                                               \
            for (int u = 0; u < 8; ++u)                                     \
                v[u] = SEGBUF[(sb * 8 + u) * 64 + lane];                    \
            unsigned short o[8];                                            \
            _Pragma("unroll")                                               \
            for (int u = 0; u < 8; ++u) {                                   \
                m = fmaf(beta, m, v[u] + bj);                               \
                bool sp = (m >= 1.0f);                                      \
                o[u] = sp ? (unsigned short)0x3F80 : (unsigned short)0;     \
                m = sp ? 0.f : m;                                           \
            }                                                               \
            _Pragma("unroll")                                               \
            for (int u = 0; u < 8; ++u)                                     \
                ((unsigned short*)S)[(size_t)(btt + sb * 8 + u) * stride + gid] = o[u]; \
        }                                                                   \
    }

    H_PREFETCH(segA, 0);
    H_PREFETCH(segB, 1);
    asm volatile("s_waitcnt vmcnt(10)" ::: "memory");  // segA resident
    __builtin_amdgcn_sched_barrier(0);
    for (int s = 0; s < nseg; s += 2) {
        H_PROC(segA, s);                               // 40 stores
        if (s + 2 < nseg) {
            H_PREFETCH(segA, s + 2);                   // 10 loads
            asm volatile("s_waitcnt vmcnt(50)" ::: "memory");  // segB resident
        } else {
            asm volatile("s_waitcnt vmcnt(40)" ::: "memory");  // segB resident
        }
        __builtin_amdgcn_sched_barrier(0);
        H_PROC(segB, s + 1);                           // 40 stores
        if (s + 3 < nseg) {
            H_PREFETCH(segB, s + 3);
            asm volatile("s_waitcnt vmcnt(50)" ::: "memory");  // segA(s+2) resident
            __builtin_amdgcn_sched_barrier(0);
        } else if (s + 2 < nseg) {
            asm volatile("s_waitcnt vmcnt(40)" ::: "memory");
            __builtin_amdgcn_sched_barrier(0);
        }
    }
    mstate[gid] = m;
#undef H_PREFETCH
#undef H_PROC
}

// ---------------- host ----------------

extern "C" void kernel_launch(void* const* d_in, const int* in_sizes, int n_in,
                              void* d_out, int out_size, void* d_ws, size_t ws_size,
                              hipStream_t stream) {
    const float* in_sp = (const float*)d_in[0];
    const float* W0 = (const float*)d_in[1];
    const float* b0 = (const float*)d_in[2];
    const float* W1 = (const float*)d_in[3];
    const float* b1 = (const float*)d_in[4];
    const float* W2 = (const float*)d_in[5];
    const float* b2 = (const float*)d_in[6];
    float* out = (float*)d_out;

    char* p = (char*)d_ws;
    auto carve = [&](size_t bytes) -> void* {
        char* r = p; p += (bytes + 255) & ~(size_t)255; return (void*)r;
    };
    u64*  MASK  = (u64*)carve((size_t)T_STEPS * NB * 8);
    bf16* BT1   = (bf16*)carve((size_t)NH * 2 * NH * 2);
    bf16* BT2   = (bf16*)carve((size_t)128 * 2 * NH * 2);
    float* m0s  = (float*)carve((size_t)NB * NH * 4);
    float* m1s  = (float*)carve((size_t)NB * NH * 4);
    float* m2s  = (float*)carve((size_t)NB * 16 * 4);
    float* I2BUF = (float*)carve((size_t)T_STEPS * NB * 16 * 4);  // full T
    u64*  BITS  = (u64*)carve((size_t)(T_STEPS / SEGO) * 256 * 8);
    size_t fixed = (size_t)(p - (char*)d_ws);

    // Tc | 4000, Tc % 400 == 0, Mc % 256 == 0
    const int tc_opts[3] = {2000, 800, 400};
    int Tc = 400;
    for (int i = 0; i < 3; ++i) {
        size_t Mc_ = (size_t)tc_opts[i] * NB;
        size_t need = fixed
            + ((Mc_ * NH * 4 + 255) & ~(size_t)255)     // IBUF
            + ((Mc_ * NH * 2 + 255) & ~(size_t)255);    // S (bf16)
        if (need <= ws_size) { Tc = tc_opts[i]; break; }
    }
    size_t Mc = (size_t)Tc * NB;
    float* IBUF = (float*)carve(Mc * NH * 4);
    bf16*  S    = (bf16*)carve(Mc * NH * 2);

    const float beta = (float)exp(-0.25 / 10.0);

    // merged prep: zero states + input masks + BT1 + BT2 in ONE launch
    int nM = NB * NH * 2 + NB * 16;
    const int ZB = (nM + 255) / 256;
    const int MB = (T_STEPS * NB) / 4;
    const int L2B = (128 * 2 * NH + 255) / 256;
    k_prep<<<ZB + MB + 256 + L2B, 256, 0, stream>>>(
        in_sp, MASK, W1, BT1, W2, BT2, m0s, nM, ZB, MB);

    const int C = T_STEPS / Tc;
    const int gx8 = (int)(Mc / 256);
    const int gthin = (int)(Mc / 64);
    for (int c = 0; c < C; ++c) {
        int t0 = c * Tc;
        // layer 0: fused MFMA scan (exact fp32 via limbs)
        k_scan_l0<<<256, 64, 0, stream>>>(MASK + (size_t)t0 * NB, W0, b0,
                                          m0s, S, Tc, beta);
        // layer 1: 256^2 8-phase GEMM; carries previous chunk's scan_out as
        // one extra block (runs concurrently, hidden under the GEMM)
        if (c == 0) {
            k_gemm8<<<gx8 * 4, 512, 0, stream>>>(S, BT1, IBUF, gx8,
                                                 nullptr, nullptr, nullptr,
                                                 nullptr, 0, 0);
        } else {
            int tp = (c - 1) * Tc;
            k_gemm8<<<gx8 * 4 + 1, 512, 0, stream>>>(
                S, BT1, IBUF, gx8,
                I2BUF + (size_t)tp * NB * 16, b2, m2s,
                BITS + (size_t)(tp / SEGO) * 256, Tc, 1);
        }
        k_scan_hidden<<<(NB * NH) / 64, 64, 0, stream>>>(IBUF, b1, m1s, S, Tc, beta);
        // layer 2: thin GEMM v2 into the full-T I2 buffer
        k_gemm_thin<<<gthin, 256, 0, stream>>>(S, BT2,
                                               I2BUF + (size_t)t0 * NB * 16);
    }
    // final chunk's output scan (bit-packed), then unpack to floats
    int tl = (C - 1) * Tc;
    k_scan_out<<<1, 256, 0, stream>>>(I2BUF + (size_t)tl * NB * 16, b2, m2s,
                                      BITS + (size_t)(tl / SEGO) * 256, Tc);
    int nOut = T_STEPS * NB * N_OUT;
    k_unpack<<<(nOut + 255) / 256, 256, 0, stream>>>(BITS, out, nOut);
}

// Round 25
// 658.137 us; speedup vs baseline: 1.1793x; 1.0005x over previous
//
#include <hip/hip_runtime.h>
#include <hip/hip_bf16.h>
#include <math.h>

// SNN forward: 64 -> 1024 -> 1024 -> 10, T=4000, B=16, LIF beta=exp(-0.025),
// thr=1, hard reset to 0, Dale clamp W>=0.
// R25 (on R24, 658us): S double-buffered by chunk parity (runtime-checked;
// falls back to R24 if ws too small) so scan_l0(c+1) is independent of
// gemm8(c) -> it rides as 32 tail blocks (8 waves = 256 one-wave units) in
// gemm8(c)'s grid, hidden under the 128us GEMM. scan_out(c-1) tail kept.
// gemm8: shared-A iteration, interleaved BT1, vmcnt(8)/(4). Merged prep.

#define T_STEPS 4000
#define NB 16
#define N_IN 64
#define NH 1024
#define N_OUT 10
#define SEGO 40
#define SEGH 40

typedef __attribute__((ext_vector_type(8))) short bf16x8;
typedef __attribute__((ext_vector_type(4))) float f32x4;
typedef __hip_bfloat16 bf16;
typedef unsigned long long u64;

#define ASG(p) (const __attribute__((address_space(1))) void*)(p)
#define ASL(p) (__attribute__((address_space(3))) void*)(p)

#define BETA_C 0.97530991202833261687f   // float(exp(-0.025))

// ---------------- merged prep kernel ----------------

__global__ __launch_bounds__(256) void k_prep(
    const float* __restrict__ in_sp, u64* __restrict__ mask,
    const float* __restrict__ W1, bf16* __restrict__ BT1,
    const float* __restrict__ W2, bf16* __restrict__ BT2,
    float* __restrict__ mst, int nM, int ZB, int MB) {
    __shared__ float Wlds[64][65];
    int b = blockIdx.x;
    const int tid = threadIdx.x;
    if (b < ZB) {                                  // zero membrane states
        int i = b * 256 + tid;
        if (i < nM) mst[i] = 0.f;
        return;
    }
    b -= ZB;
    if (b < MB) {                                  // input spike masks
        int w = b * 4 + (tid >> 6);
        int lane = tid & 63;
        float v = in_sp[(size_t)w * 64 + lane];
        u64 bal = __ballot(v > 0.5f);
        if (lane == 0) mask[w] = bal;
        return;
    }
    b -= MB;
    if (b < 256) {                                 // limbs_t: BT1 interleaved
        const int lane = tid & 63;
        const int wr   = tid >> 6;
        const int k0 = (b & 15) * 64;
        const int n0 = (b >> 4) * 64;
#pragma unroll
        for (int rr = 0; rr < 16; ++rr) {
            int kl = wr * 16 + rr;
            Wlds[kl][lane] = W1[(size_t)(k0 + kl) * 1024 + n0 + lane];
        }
        __syncthreads();
#pragma unroll
        for (int rr = 0; rr < 16; ++rr) {
            int nl = wr * 16 + rr;
            float w = fmaxf(Wlds[lane][nl], 0.f);  // Dale's law clamp
            bf16 h = __float2bfloat16(w);
            float hf = __bfloat162float(h);
            bf16 l = __float2bfloat16(w - hf);
            size_t base = (size_t)(n0 + nl) * 2048 + 2 * k0 + lane;
            BT1[base] = h;
            BT1[base + 64] = l;
        }
        return;
    }
    b -= 256;
    {                                              // limbs: BT2 [128][2048]
        int idx = b * 256 + tid;
        int total = 128 * 2 * NH;
        if (idx >= total) return;
        int n  = idx / (2 * NH);
        int k2 = idx - n * (2 * NH);
        int lo = (k2 >= NH);
        int k = lo ? (k2 - NH) : k2;
        float v = 0.f;
        if (n < N_OUT) {
            float w = fmaxf(W2[(size_t)k * N_OUT + n], 0.f);
            float hi = __bfloat162float(__float2bfloat16(w));
            v = lo ? (w - hi) : w;
        }
        BT2[idx] = __float2bfloat16(v);
    }
}

// Unpack scan_out bit-spikes.
__global__ void k_unpack(const u64* __restrict__ BITS, float* __restrict__ out,
                         int total) {
    int idx = blockIdx.x * 256 + threadIdx.x;
    if (idx >= total) return;
    int t   = idx / (NB * N_OUT);
    int rem = idx - t * (NB * N_OUT);
    int b = rem / N_OUT;
    int k = rem - b * N_OUT;
    u64 w = BITS[(size_t)(t / SEGO) * 256 + b * 16 + k];
    out[idx] = ((w >> (t % SEGO)) & 1ULL) ? 1.f : 0.f;
}

// ---------------- scan_out body (standalone + gemm8 tail) ----------------

__device__ __forceinline__ void scan_out_body(
    const float* __restrict__ I2, const float* __restrict__ bias,
    float* __restrict__ mstate, u64* __restrict__ BITS,
    int Tc, float* seg, int tid) {
    float* segA = seg;
    float* segB = seg + SEGO * 256;
    const bool act = tid < 256;
    const int lane = tid & 63;
    const int wave = tid >> 6;
    const int k = tid & 15;
    float m = 0.f, bj = 0.f;
    if (act) {
        m = mstate[tid];
        bj = (k < N_OUT) ? bias[k] : 0.f;
    }
    const int nseg = Tc / SEGO;                  // even

#define O_PREFETCH(SEGBUF, SIDX)                                            \
    if (act) {                                                              \
        const float* src = I2 + (size_t)(SIDX) * SEGO * 256                 \
                              + (size_t)wave * 256 + lane * 4;              \
        _Pragma("unroll")                                                   \
        for (int g = 0; g < SEGO / 4; ++g)                                  \
            __builtin_amdgcn_global_load_lds(                               \
                ASG(src + (size_t)(g * 4) * 256),                           \
                ASL(&SEGBUF[(g * 4 + wave) * 256]), 16, 0, 0);              \
    }

#define O_PROC(SEGBUF, SIDX)                                                \
    if (act) {                                                              \
        u64 obits = 0;                                                      \
        _Pragma("unroll")                                                   \
        for (int sb = 0; sb < SEGO / 8; ++sb) {                             \
            float v[8];                                                     \
            _Pragma("unroll")                                               \
            for (int u = 0; u < 8; ++u)                                     \
                v[u] = SEGBUF[(sb * 8 + u) * 256 + tid];                    \
            _Pragma("unroll")                                               \
            for (int u = 0; u < 8; ++u) {                                   \
                m = fmaf(BETA_C, m, v[u] + bj);                             \
                bool sp = (m >= 1.0f);                                      \
                obits |= ((u64)(sp ? 1 : 0)) << (sb * 8 + u);               \
                m = sp ? 0.f : m;                                           \
            }                                                               \
        }                                                                   \
        BITS[(size_t)(SIDX) * 256 + tid] = obits;                           \
    }

    O_PREFETCH(segA, 0);
    O_PREFETCH(segB, 1);
    asm volatile("s_waitcnt vmcnt(10)" ::: "memory");
    __builtin_amdgcn_sched_barrier(0);
    __builtin_amdgcn_s_barrier();
    for (int s = 0; s < nseg; s += 2) {
        O_PROC(segA, s);
        if (s + 2 < nseg) {
            O_PREFETCH(segA, s + 2);
            asm volatile("s_waitcnt vmcnt(11)" ::: "memory");
        } else {
            asm volatile("s_waitcnt vmcnt(1)" ::: "memory");
        }
        __builtin_amdgcn_sched_barrier(0);
        __builtin_amdgcn_s_barrier();
        O_PROC(segB, s + 1);
        if (s + 3 < nseg) {
            O_PREFETCH(segB, s + 3);
            asm volatile("s_waitcnt vmcnt(11)" ::: "memory");
            __builtin_amdgcn_sched_barrier(0);
            __builtin_amdgcn_s_barrier();
        } else if (s + 2 < nseg) {
            asm volatile("s_waitcnt vmcnt(1)" ::: "memory");
            __builtin_amdgcn_sched_barrier(0);
            __builtin_amdgcn_s_barrier();
        }
    }
    if (act) mstate[tid] = m;
#undef O_PREFETCH
#undef O_PROC
}

__global__ __launch_bounds__(256) void k_scan_out(
    const float* __restrict__ I2, const float* __restrict__ bias,
    float* __restrict__ mstate, u64* __restrict__ BITS, int Tc) {
    __shared__ __align__(16) float seg[2 * SEGO * 256];
    scan_out_body(I2, bias, mstate, BITS, Tc, seg, threadIdx.x);
}

// ---------------- scan_l0 body (standalone + gemm8 tail) ----------------
// One "unit" = one wave handling (b, q): 64 cols of layer 0. IL = per-unit
// LDS region of 2*16*68 floats. s_barrier count uniform across co-resident
// waves (all run ntile iterations).

__device__ __forceinline__ void scan_l0_body(
    const u64* __restrict__ mask, const float* __restrict__ W0,
    const float* __restrict__ bias, float* __restrict__ mstate,
    bf16* __restrict__ S, int Tc, int b0, int lane, float* IL) {
    const int b  = b0 >> 4;
    const int q  = b0 & 15;
    const int j0 = q * 64;
    const int gid = b0 * 64 + lane;
    const int r16 = lane & 15;
    const int kg  = lane >> 4;
    bf16x8 bh[4][2], bl[4][2];
#pragma unroll
    for (int jt = 0; jt < 4; ++jt)
#pragma unroll
        for (int kk = 0; kk < 2; ++kk)
#pragma unroll
            for (int e = 0; e < 8; ++e) {
                int k = kk * 32 + kg * 8 + e;
                float w = fmaxf(W0[(size_t)k * 1024 + j0 + jt * 16 + r16], 0.f);
                bf16 h = __float2bfloat16(w);
                float hf = __bfloat162float(h);
                bf16 l = __float2bfloat16(w - hf);
                bh[jt][kk][e] = *(short*)&h;
                bl[jt][kk][e] = *(short*)&l;
            }
    float m = mstate[gid];
    const float bj = bias[j0 + lane];
    const size_t stride = (size_t)NB * NH;
    const int ntile = Tc / 16;
    const int tmax = ntile - 1;

#define LOADM(TT) mask[(size_t)(((TT) <= tmax ? (TT) : tmax) * 16 + r16) * NB + b]

#define L0_COMPUTE(MSK, P)                                                  \
    {                                                                       \
        f32x4 acc[4] = {};                                                  \
        _Pragma("unroll")                                                   \
        for (int kk = 0; kk < 2; ++kk) {                                    \
            unsigned byte8 = (unsigned)(((MSK) >> (kk * 32 + kg * 8)) & 0xFF); \
            bf16x8 af;                                                      \
            _Pragma("unroll")                                               \
            for (int e = 0; e < 8; ++e)                                     \
                af[e] = ((byte8 >> e) & 1) ? (short)0x3F80 : (short)0;      \
            _Pragma("unroll")                                               \
            for (int jt = 0; jt < 4; ++jt) {                                \
                acc[jt] = __builtin_amdgcn_mfma_f32_16x16x32_bf16(          \
                    af, bh[jt][kk], acc[jt], 0, 0, 0);                      \
                acc[jt] = __builtin_amdgcn_mfma_f32_16x16x32_bf16(          \
                    af, bl[jt][kk], acc[jt], 0, 0, 0);                      \
            }                                                               \
        }                                                                   \
        _Pragma("unroll")                                                   \
        for (int jt = 0; jt < 4; ++jt)                                      \
            _Pragma("unroll")                                               \
            for (int rr = 0; rr < 4; ++rr)                                  \
                IL[(P) * 1088 + (kg * 4 + rr) * 68 + jt * 16 + r16] = acc[jt][rr]; \
    }

    u64 mc = LOADM(0);
    L0_COMPUTE(mc, 0);
    u64 mn = LOADM(1);
    for (int tt = 0; tt < ntile; ++tt) {
        __builtin_amdgcn_s_barrier();            // tile tt resident
        float v[16];
#pragma unroll
        for (int u = 0; u < 16; ++u)
            v[u] = IL[(tt & 1) * 1088 + u * 68 + lane];
        u64 m2 = LOADM(tt + 2);
        if (tt + 1 < ntile) L0_COMPUTE(mn, (tt + 1) & 1);
        unsigned short o[16];
#pragma unroll
        for (int u = 0; u < 16; ++u) {
            m = fmaf(BETA_C, m, v[u] + bj);
            bool sp = (m >= 1.0f);
            o[u] = sp ? (unsigned short)0x3F80 : (unsigned short)0;
            m = sp ? 0.f : m;
        }
#pragma unroll
        for (int u = 0; u < 16; ++u)
            ((unsigned short*)S)[(size_t)(tt * 16 + u) * stride + gid] = o[u];
        mn = m2;
    }
    mstate[gid] = m;
#undef L0_COMPUTE
#undef LOADM
}

__global__ __launch_bounds__(64) void k_scan_l0(
    const u64* __restrict__ mask, const float* __restrict__ W0,
    const float* __restrict__ bias, float* __restrict__ mstate,
    bf16* __restrict__ S, int Tc) {
    __shared__ __align__(16) float IL[2 * 16 * 68];
    scan_l0_body(mask, W0, bias, mstate, S, Tc, blockIdx.x, threadIdx.x, IL);
}

// ---------------- thin GEMM v2 (layer 2) ----------------

__global__ __launch_bounds__(256) void k_gemm_thin(
    const bf16* __restrict__ A, const bf16* __restrict__ BT,
    float* __restrict__ C) {
    const int tid  = threadIdx.x;
    const int lane = tid & 63;
    const int wave = tid >> 6;
    const int r16 = lane & 15;
    const int kg  = lane >> 4;
    const int m0 = blockIdx.x * 64 + wave * 16;
    f32x4 acc = {};
    const bf16* ap = A + (size_t)(m0 + r16) * 1024 + kg * 8;
    const bf16* bh = BT + (size_t)r16 * 2048 + kg * 8;
    const bf16* bl = bh + 1024;
#pragma unroll 8
    for (int kt = 0; kt < 32; ++kt) {
        const int ka = kt * 32;
        bf16x8 af  = *(const bf16x8*)(ap + ka);
        bf16x8 bfh = *(const bf16x8*)(bh + ka);
        bf16x8 bfl = *(const bf16x8*)(bl + ka);
        acc = __builtin_amdgcn_mfma_f32_16x16x32_bf16(af, bfh, acc, 0, 0, 0);
        acc = __builtin_amdgcn_mfma_f32_16x16x32_bf16(af, bfl, acc, 0, 0, 0);
    }
#pragma unroll
    for (int rr = 0; rr < 4; ++rr)
        C[(size_t)(m0 + kg * 4 + rr) * 16 + r16] = acc[rr];
}

// ---------------- 256^2 8-phase GEMM (layer 1), shared-A iteration ---------
// + tail blocks: [0,doTailOut) scan_out(c-1); next nL0/8... (32 blocks) run
// scan_l0(c+1) as 8 one-wave units each.

__global__ __launch_bounds__(512) void k_gemm8(
    const bf16* __restrict__ A, const bf16* __restrict__ BT,
    float* __restrict__ C, int gx,
    const float* __restrict__ I2t, const float* __restrict__ b2t,
    float* __restrict__ m2t, u64* __restrict__ BITSt, int tcT, int doTailOut,
    const u64* __restrict__ maskN, const float* __restrict__ W0N,
    const float* __restrict__ b0N, float* __restrict__ m0N,
    bf16* __restrict__ SN, int nL0blk) {
    __shared__ __align__(16) char LDS[131072];
    const int tid  = threadIdx.x;
    const int lane = tid & 63;
    const int wave = tid >> 6;

    const int nwg = gridDim.x - doTailOut - nL0blk;
    const int wg  = blockIdx.x;
    if (wg >= nwg) {
        int tix = wg - nwg;
        if (tix < doTailOut) {
            scan_out_body(I2t, b2t, m2t, BITSt, tcT, (float*)LDS, tid);
        } else {
            int unit = (tix - doTailOut) * 8 + wave;
            float* IL = (float*)LDS + wave * 2176;
            scan_l0_body(maskN, W0N, b0N, m0N, SN, tcT, unit, lane, IL);
        }
        return;
    }

    const int KA = 1024;
    const int q = nwg >> 3, r = nwg & 7;
    const int xcd = wg & 7, idx0 = wg >> 3;
    const int swz = (xcd < r ? xcd * (q + 1) : r * (q + 1) + (xcd - r) * q) + idx0;
    const int gy = nwg / gx;              // 4
    const int n0 = (swz % gy) * 256;
    const int m0 = (swz / gy) * 256;

    const int wm = (wave >> 2) * 128;
    const int wn = (wave & 3) * 64;
    const int r16l = lane & 15;
    const int kg   = lane >> 4;
    const int hA   = wave >> 2;
    const int hB   = (wave & 3) >> 1;
    const int wn64 = wave & 1;

    const int po = (r16l * 64 + kg * 16) ^ (((r16l >> 3) & 1) << 5);
    const char* bA[2] = { LDS + hA * 16384 + po,
                          LDS + 32768 + hA * 16384 + po };
    const char* bB[2] = { LDS + 65536 + hB * 16384 + po,
                          LDS + 98304 + hB * 16384 + po };
    const int bOff = wn64 * 8192;

    int s_row[2], s_col[2];
#pragma unroll
    for (int rr = 0; rr < 2; ++rr) {
        int d = (rr * 512 + tid) * 16;
        int l = d ^ (((d >> 9) & 1) << 5);
        int sub = l >> 10;
        int w = l & 1023;
        s_row[rr] = (sub >> 1) * 16 + (w >> 6);
        s_col[rr] = ((sub & 1) * 64 + (w & 63)) >> 1;
    }

#define STAGE_A(ADST, HALF, K0)                                             \
    {                                                                       \
        _Pragma("unroll")                                                   \
        for (int rr = 0; rr < 2; ++rr)                                      \
            __builtin_amdgcn_global_load_lds(                               \
                ASG(A + (size_t)(m0 + (HALF) * 128 + s_row[rr]) * KA        \
                    + (K0) + s_col[rr]),                                    \
                ASL(LDS + (ADST) * 32768 + (HALF) * 16384                   \
                    + (rr * 512 + wave * 64) * 16),                         \
                16, 0, 0);                                                  \
    }
#define STAGE_B(BUF, HALF, K0)                                              \
    {                                                                       \
        _Pragma("unroll")                                                   \
        for (int rr = 0; rr < 2; ++rr)                                      \
            __builtin_amdgcn_global_load_lds(                               \
                ASG(BT + (size_t)(n0 + (HALF) * 128 + s_row[rr]) * 2048     \
                    + (K0) + s_col[rr]),                                    \
                ASL(LDS + 65536 + (BUF) * 32768 + (HALF) * 16384            \
                    + (rr * 512 + wave * 64) * 16),                         \
                16, 0, 0);                                                  \
    }

    f32x4 acc[8][4] = {};
    bf16x8 a[4][2], b[4][2];

#define MM(MIB, NIB)                                                        \
    {                                                                       \
        _Pragma("unroll")                                                   \
        for (int i = 0; i < 4; ++i)                                         \
            _Pragma("unroll")                                               \
            for (int j = 0; j < 2; ++j) {                                   \
                acc[(MIB) + i][(NIB) + j] =                                 \
                    __builtin_amdgcn_mfma_f32_16x16x32_bf16(                \
                        a[i][0], b[(NIB) + j][0], acc[(MIB) + i][(NIB) + j], 0, 0, 0); \
                acc[(MIB) + i][(NIB) + j] =                                 \
                    __builtin_amdgcn_mfma_f32_16x16x32_bf16(                \
                        a[i][1], b[(NIB) + j][1], acc[(MIB) + i][(NIB) + j], 0, 0, 0); \
            }                                                               \
    }

#define PH_SYNC()                                                           \
    __builtin_amdgcn_s_barrier();                                           \
    asm volatile("s_waitcnt lgkmcnt(0)" ::: "memory");                      \
    __builtin_amdgcn_sched_barrier(0);

#define KT_EVEN(ABUF, BKN, AKN)                                             \
    {                                                                       \
        _Pragma("unroll")                                                   \
        for (int i = 0; i < 4; ++i) {                                       \
            a[i][0] = *(const bf16x8*)(bA[ABUF] + i * 2048);                \
            a[i][1] = *(const bf16x8*)(bA[ABUF] + i * 2048 + 1024);         \
        }                                                                   \
        _Pragma("unroll")                                                   \
        for (int j = 0; j < 2; ++j) {                                       \
            b[j][0] = *(const bf16x8*)(bB[0] + bOff + j * 2048);            \
            b[j][1] = *(const bf16x8*)(bB[0] + bOff + j * 2048 + 1024);     \
        }                                                                   \
        PH_SYNC();                                                          \
        __builtin_amdgcn_s_setprio(1);                                      \
        MM(0, 0);                                                           \
        __builtin_amdgcn_s_setprio(0);                                      \
        __builtin_amdgcn_s_barrier();                                       \
        _Pragma("unroll")                                                   \
        for (int j = 0; j < 2; ++j) {                                       \
            b[2 + j][0] = *(const bf16x8*)(bB[0] + bOff + (2 + j) * 2048);  \
            b[2 + j][1] = *(const bf16x8*)(bB[0] + bOff + (2 + j) * 2048 + 1024); \
        }                                                                   \
        PH_SYNC();                                                          \
        __builtin_amdgcn_s_setprio(1);                                      \
        MM(0, 2);                                                           \
        __builtin_amdgcn_s_setprio(0);                                      \
        __builtin_amdgcn_s_barrier();                                       \
        _Pragma("unroll")                                                   \
        for (int i = 0; i < 4; ++i) {                                       \
            a[i][0] = *(const bf16x8*)(bA[ABUF] + (4 + i) * 2048);          \
            a[i][1] = *(const bf16x8*)(bA[ABUF] + (4 + i) * 2048 + 1024);   \
        }                                                                   \
        STAGE_B(0, 0, BKN);                                                 \
        STAGE_B(0, 1, BKN);                                                 \
        PH_SYNC();                                                          \
        __builtin_amdgcn_s_setprio(1);                                      \
        MM(4, 0);                                                           \
        __builtin_amdgcn_s_setprio(0);                                      \
        __builtin_amdgcn_s_barrier();                                       \
        STAGE_A((ABUF) ^ 1, 0, AKN);                                        \
        STAGE_A((ABUF) ^ 1, 1, AKN);                                        \
        PH_SYNC();                                                          \
        __builtin_amdgcn_s_setprio(1);                                      \
        MM(4, 2);                                                           \
        __builtin_amdgcn_s_setprio(0);                                      \
        asm volatile("s_waitcnt vmcnt(8)" ::: "memory");                    \
        __builtin_amdgcn_sched_barrier(0);                                  \
        __builtin_amdgcn_s_barrier();                                       \
    }

#define KT_ODD(ABUF, BKN)                                                   \
    {                                                                       \
        _Pragma("unroll")                                                   \
        for (int i = 0; i < 4; ++i) {                                       \
            a[i][0] = *(const bf16x8*)(bA[ABUF] + i * 2048);                \
            a[i][1] = *(const bf16x8*)(bA[ABUF] + i * 2048 + 1024);         \
        }                                                                   \
        _Pragma("unroll")                                                   \
        for (int j = 0; j < 2; ++j) {                                       \
            b[j][0] = *(const bf16x8*)(bB[1] + bOff + j * 2048);            \
            b[j][1] = *(const bf16x8*)(bB[1] + bOff + j * 2048 + 1024);     \
        }                                                                   \
        PH_SYNC();                                                          \
        __builtin_amdgcn_s_setprio(1);                                      \
        MM(0, 0);                                                           \
        __builtin_amdgcn_s_setprio(0);                                      \
        __builtin_amdgcn_s_barrier();                                       \
        _Pragma("unroll")                                                   \
        for (int j = 0; j < 2; ++j) {                                       \
            b[2 + j][0] = *(const bf16x8*)(bB[1] + bOff + (2 + j) * 2048);  \
            b[2 + j][1] = *(const bf16x8*)(bB[1] + bOff + (2 + j) * 2048 + 1024); \
        }                                                                   \
        PH_SYNC();                                                          \
        __builtin_amdgcn_s_setprio(1);                                      \
        MM(0, 2);                                                           \
        __builtin_amdgcn_s_setprio(0);                                      \
        __builtin_amdgcn_s_barrier();                                       \
        _Pragma("unroll")                                                   \
        for (int i = 0; i < 4; ++i) {                                       \
            a[i][0] = *(const bf16x8*)(bA[ABUF] + (4 + i) * 2048);          \
            a[i][1] = *(const bf16x8*)(bA[ABUF] + (4 + i) * 2048 + 1024);   \
        }                                                                   \
        STAGE_B(1, 0, BKN);                                                 \
        STAGE_B(1, 1, BKN);                                                 \
        PH_SYNC();                                                          \
        __builtin_amdgcn_s_setprio(1);                                      \
        MM(4, 0);                                                           \
        __builtin_amdgcn_s_setprio(0);                                      \
        __builtin_amdgcn_s_barrier();                                       \
        PH_SYNC();                                                          \
        __builtin_amdgcn_s_setprio(1);                                      \
        MM(4, 2);                                                           \
        __builtin_amdgcn_s_setprio(0);                                      \
        asm volatile("s_waitcnt vmcnt(4)" ::: "memory");                    \
        __builtin_amdgcn_sched_barrier(0);                                  \
        __builtin_amdgcn_s_barrier();                                       \
    }

    STAGE_B(0, 0, 0);  STAGE_B(0, 1, 0);
    STAGE_A(0, 0, 0);  STAGE_A(0, 1, 0);
    STAGE_B(1, 0, 64); STAGE_B(1, 1, 64);
    asm volatile("s_waitcnt vmcnt(4)" ::: "memory");
    __builtin_amdgcn_sched_barrier(0);
    __builtin_amdgcn_s_barrier();

    for (int it2 = 0; it2 < 16; it2 += 2) {
        const int ak1 = (64 * (it2 + 1)) & 1023;
        const int be1 = (128 * (it2 + 1)) & 2047;
        KT_EVEN(0, be1, ak1);
        KT_ODD(0, be1 + 64);
        const int ak2 = (64 * (it2 + 2)) & 1023;
        const int be2 = (128 * (it2 + 2)) & 2047;
        KT_EVEN(1, be2, ak2);
        KT_ODD(1, be2 + 64);
    }
    asm volatile("s_waitcnt vmcnt(0)" ::: "memory");
    __builtin_amdgcn_sched_barrier(0);

#pragma unroll
    for (int mi = 0; mi < 8; ++mi)
#pragma unroll
        for (int ni = 0; ni < 4; ++ni)
#pragma unroll
            for (int rr = 0; rr < 4; ++rr) {
                int row = m0 + wm + mi * 16 + kg * 4 + rr;
                int col = n0 + wn + ni * 16 + r16l;
                C[(size_t)row * 1024 + col] = acc[mi][ni][rr];
            }
#undef KT_ODD
#undef KT_EVEN
#undef PH_SYNC
#undef MM
#undef STAGE_A
#undef STAGE_B
}

// ---------------- hidden layer 1 scan ----------------

__global__ __launch_bounds__(64) void k_scan_hidden(
    const float* __restrict__ I, const float* __restrict__ bias,
    float* __restrict__ mstate, bf16* __restrict__ S, int Tc, float beta) {
    __shared__ __align__(16) float segA[SEGH * 64];
    __shared__ __align__(16) float segB[SEGH * 64];
    const int lane = threadIdx.x;
    const int gid  = blockIdx.x * 64 + lane;
    const int j = gid & (NH - 1);
    float m = mstate[gid];
    const float bj = bias[j];
    const size_t stride = (size_t)NB * NH;
    const int nseg = Tc / SEGH;                  // even
    const int lrow = lane >> 4;
    const int lcol = (lane & 15) << 2;

#define H_PREFETCH(SEGBUF, SIDX)                                            \
    {                                                                       \
        const float* src = I + (size_t)(SIDX) * SEGH * stride               \
                             + (size_t)lrow * stride + blockIdx.x * 64 + lcol; \
        _Pragma("unroll")                                                   \
        for (int g = 0; g < SEGH / 4; ++g)                                  \
            __builtin_amdgcn_global_load_lds(                               \
                ASG(src + (size_t)(g * 4) * stride),                        \
                ASL(&SEGBUF[g * 256]), 16, 0, 0);                           \
    }

#define H_PROC(SEGBUF, SIDX)                                                \
    {                                                                       \
        const int btt = (SIDX) * SEGH;                                      \
        _Pragma("unroll")                                                   \
        for (int sb = 0; sb < SEGH / 8; ++sb) {                             \
            float v[8];                                                     \
            _Pragma("unroll")                                               \
            for (int u = 0; u < 8; ++u)                                     \
                v[u] = SEGBUF[(sb * 8 + u) * 64 + lane];                    \
            unsigned short o[8];                                            \
            _Pragma("unroll")                                               \
            for (int u = 0; u < 8; ++u) {                                   \
                m = fmaf(beta, m, v[u] + bj);                               \
                bool sp = (m >= 1.0f);                                      \
                o[u] = sp ? (unsigned short)0x3F80 : (unsigned short)0;     \
                m = sp ? 0.f : m;                                           \
            }                                                               \
            _Pragma("unroll")                                               \
            for (int u = 0; u < 8; ++u)                                     \
                ((unsigned short*)S)[(size_t)(btt + sb * 8 + u) * stride + gid] = o[u]; \
        }                                                                   \
    }

    H_PREFETCH(segA, 0);
    H_PREFETCH(segB, 1);
    asm volatile("s_waitcnt vmcnt(10)" ::: "memory");
    __builtin_amdgcn_sched_barrier(0);
    for (int s = 0; s < nseg; s += 2) {
        H_PROC(segA, s);
        if (s + 2 < nseg) {
            H_PREFETCH(segA, s + 2);
            asm volatile("s_waitcnt vmcnt(50)" ::: "memory");
        } else {
            asm volatile("s_waitcnt vmcnt(40)" ::: "memory");
        }
        __builtin_amdgcn_sched_barrier(0);
        H_PROC(segB, s + 1);
        if (s + 3 < nseg) {
            H_PREFETCH(segB, s + 3);
            asm volatile("s_waitcnt vmcnt(50)" ::: "memory");
            __builtin_amdgcn_sched_barrier(0);
        } else if (s + 2 < nseg) {
            asm volatile("s_waitcnt vmcnt(40)" ::: "memory");
            __builtin_amdgcn_sched_barrier(0);
        }
    }
    mstate[gid] = m;
#undef H_PREFETCH
#undef H_PROC
}

// ---------------- host ----------------

extern "C" void kernel_launch(void* const* d_in, const int* in_sizes, int n_in,
                              void* d_out, int out_size, void* d_ws, size_t ws_size,
                              hipStream_t stream) {
    const float* in_sp = (const float*)d_in[0];
    const float* W0 = (const float*)d_in[1];
    const float* b0 = (const float*)d_in[2];
    const float* W1 = (const float*)d_in[3];
    const float* b1 = (const float*)d_in[4];
    const float* W2 = (const float*)d_in[5];
    const float* b2 = (const float*)d_in[6];
    float* out = (float*)d_out;

    char* p = (char*)d_ws;
    auto carve = [&](size_t bytes) -> void* {
        char* r = p; p += (bytes + 255) & ~(size_t)255; return (void*)r;
    };
    u64*  MASK  = (u64*)carve((size_t)T_STEPS * NB * 8);
    bf16* BT1   = (bf16*)carve((size_t)NH * 2 * NH * 2);
    bf16* BT2   = (bf16*)carve((size_t)128 * 2 * NH * 2);
    float* m0s  = (float*)carve((size_t)NB * NH * 4);
    float* m1s  = (float*)carve((size_t)NB * NH * 4);
    float* m2s  = (float*)carve((size_t)NB * 16 * 4);
    float* I2BUF = (float*)carve((size_t)T_STEPS * NB * 16 * 4);  // full T
    u64*  BITS  = (u64*)carve((size_t)(T_STEPS / SEGO) * 256 * 8);
    size_t fixed = (size_t)(p - (char*)d_ws);

    // Tc | 4000, Tc % 400 == 0, Mc % 256 == 0 (base need: IBUF + one S)
    const int tc_opts[3] = {2000, 800, 400};
    int Tc = 400;
    for (int i = 0; i < 3; ++i) {
        size_t Mc_ = (size_t)tc_opts[i] * NB;
        size_t need = fixed
            + ((Mc_ * NH * 4 + 255) & ~(size_t)255)     // IBUF
            + ((Mc_ * NH * 2 + 255) & ~(size_t)255);    // S (bf16)
        if (need <= ws_size) { Tc = tc_opts[i]; break; }
    }
    size_t Mc = (size_t)Tc * NB;
    float* IBUF = (float*)carve(Mc * NH * 4);
    bf16*  S0   = (bf16*)carve(Mc * NH * 2);
    // optional second S buffer for chunk-parity double-buffering
    size_t sbytes = (Mc * NH * 2 + 255) & ~(size_t)255;
    int sdbuf = ((size_t)(p - (char*)d_ws) + sbytes <= ws_size) ? 1 : 0;
    bf16* S1 = sdbuf ? (bf16*)carve(Mc * NH * 2) : S0;
    auto Sb = [&](int c) -> bf16* { return (c & 1) ? S1 : S0; };

    // merged prep
    int nM = NB * NH * 2 + NB * 16;
    const int ZB = (nM + 255) / 256;
    const int MB = (T_STEPS * NB) / 4;
    const int L2B = (128 * 2 * NH + 255) / 256;
    k_prep<<<ZB + MB + 256 + L2B, 256, 0, stream>>>(
        in_sp, MASK, W1, BT1, W2, BT2, m0s, nM, ZB, MB);

    const int C = T_STEPS / Tc;
    const int gx8 = (int)(Mc / 256);
    const int gthin = (int)(Mc / 64);

    // chunk 0's layer-0 scan (standalone)
    k_scan_l0<<<256, 64, 0, stream>>>(MASK, W0, b0, m0s, Sb(0), Tc);

    const float beta = (float)exp(-0.25 / 10.0);
    for (int c = 0; c < C; ++c) {
        int t0 = c * Tc;
        // layer 1 GEMM; tails: scan_out(c-1) [1 blk] + scan_l0(c+1) [32 blk]
        int doOut = (c >= 1) ? 1 : 0;
        int nL0   = (sdbuf && c + 1 < C) ? 32 : 0;
        int tp = (c - 1) * Tc;
        k_gemm8<<<gx8 * 4 + doOut + nL0, 512, 0, stream>>>(
            Sb(c), BT1, IBUF, gx8,
            doOut ? I2BUF + (size_t)tp * NB * 16 : nullptr, b2, m2s,
            doOut ? BITS + (size_t)(tp / SEGO) * 256 : nullptr, Tc, doOut,
            nL0 ? MASK + (size_t)(t0 + Tc) * NB : nullptr, W0, b0, m0s,
            nL0 ? Sb(c + 1) : nullptr, nL0);
        k_scan_hidden<<<(NB * NH) / 64, 64, 0, stream>>>(IBUF, b1, m1s, Sb(c), Tc, beta);
        k_gemm_thin<<<gthin, 256, 0, stream>>>(Sb(c), BT2,
                                               I2BUF + (size_t)t0 * NB * 16);
        // without S dbuf, run next chunk's scan_l0 standalone (after thin)
        if (!sdbuf && c + 1 < C)
            k_scan_l0<<<256, 64, 0, stream>>>(MASK + (size_t)(t0 + Tc) * NB,
                                              W0, b0, m0s, Sb(c + 1), Tc);
    }
    // final chunk's output scan, then unpack
    int tl = (C - 1) * Tc;
    k_scan_out<<<1, 256, 0, stream>>>(I2BUF + (size_t)tl * NB * 16, b2, m2s,
                                      BITS + (size_t)(tl / SEGO) * 256, Tc);
    int nOut = T_STEPS * NB * N_OUT;
    k_unpack<<<(nOut + 255) / 256, 256, 0, stream>>>(BITS, out, nOut);
}